// Round 1
// 152.417 us; speedup vs baseline: 1.0683x; 1.0683x over previous
//
#include <hip/hip_runtime.h>
#include <math.h>

// ---------------------------------------------------------------------------
// GeoFeatureExtractor: B=256, T=512, N=51 landmarks x 3 (fp32), 114 features.
// Round 6: kill the scattered-store transaction storm.
//   rocprof showed WRITE_SIZE 91 MB vs 58.4 MB ideal (1.56x write
//   amplification) and 57 float2 stores/lane at 456 B lane stride = 64 cache
//   lines touched PER STORE INSTRUCTION (~3650 line transactions per block).
//   Fix: stage F[114] into LDS as the exact byte image of the block's
//   64x456 B output region (stride 114 floats, reusing the Sh0/Sh1 union),
//   then burst-copy with 29 aligned dwordx4 stores (fully-covered lines,
//   no RMW, 8x fewer transactions).
// Structure otherwise unchanged from round 5 (66 us/dispatch):
//   one wave per block, all staging via __builtin_amdgcn_global_load_lds,
//   Hastings acos, __expf, v_rcp/v_sqrt intrinsics. LDS 35.9 KB -> 4/CU.
// ---------------------------------------------------------------------------

#define NF   114
#define NC   153
#define TILE 64
#define HSTR 65                 // hand buffer stride (65 = odd -> conflict-free)
#define FSTR 33                 // face buffer stride (odd)
#define HALO 4
#define HN   (TILE + 2 * HALO)  // 72 halo timesteps

#if defined(__has_builtin)
#if __has_builtin(__builtin_amdgcn_global_load_lds)
#define USE_DMA 1
#endif
#endif
#ifndef USE_DMA
#define USE_DMA 0
#endif

typedef const __attribute__((address_space(1))) void gas_t;
typedef __attribute__((address_space(3))) void las_t;

// per-lane global addr g; LDS dest = uniform base `lds` + lane*4 (exec-masked)
__device__ __forceinline__ void dma4(const float* g, float* lds) {
#if USE_DMA
    __builtin_amdgcn_global_load_lds((gas_t*)g, (las_t*)lds, 4, 0, 0);
#else
    lds[threadIdx.x & 63] = *g;
#endif
}

struct V3 { float x, y, z; };

__device__ __forceinline__ V3 operator-(V3 a, V3 b) { return {a.x - b.x, a.y - b.y, a.z - b.z}; }
__device__ __forceinline__ V3 operator+(V3 a, V3 b) { return {a.x + b.x, a.y + b.y, a.z + b.z}; }
__device__ __forceinline__ V3 operator*(V3 a, float s) { return {a.x * s, a.y * s, a.z * s}; }
__device__ __forceinline__ float dot3(V3 a, V3 b) { return a.x * b.x + a.y * b.y + a.z * b.z; }
__device__ __forceinline__ V3 cross3(V3 a, V3 b) {
    return {a.y * b.z - a.z * b.y, a.z * b.x - a.x * b.z, a.x * b.y - a.y * b.x};
}

__device__ __forceinline__ float fsqrt(float x) { return __builtin_amdgcn_sqrtf(x); }
__device__ __forceinline__ float frcp(float x)  { return __builtin_amdgcn_rcpf(x); }

__device__ __forceinline__ float norm3(V3 a) { return fsqrt(dot3(a, a)); }
__device__ __forceinline__ float dist3(V3 a, V3 b) { V3 d = a - b; return fsqrt(dot3(d, d) + 1e-6f); }

// clip + Hastings acos approximation, |err| < 7e-5 rad (threshold is 2.45)
__device__ __forceinline__ float acosc(float c) {
    c = fminf(fmaxf(c, -1.0f + 1e-6f), 1.0f - 1e-6f);
    float ax = fabsf(c);
    float r = fsqrt(1.0f - ax) *
              (1.5707288f + ax * (-0.2121144f + ax * (0.0742610f - 0.0187293f * ax)));
    return c < 0.0f ? 3.14159265358979f - r : r;
}

// boundary-mapped central-diff endpoints (exact _cdiff semantics)
__device__ __forceinline__ void bmap(int tt, int T, int& ta, int& tb) {
    if (tt == 0)          { ta = 0;      tb = 2;     }
    else if (tt == T - 1) { ta = T - 3;  tb = T - 1; }
    else                  { ta = tt - 1; tb = tt + 1; }
}

__global__ __launch_bounds__(64, 2) void geo_fused(
    const float* __restrict__ xyz,
    const float* __restrict__ fmask,
    const float* __restrict__ bmask,
    float* __restrict__ out,
    int T)
{
    // Union buffer: phases overlay it.
    //   [staging]  Sh0 = S (hand0, later face rows), Sh1 = S+TILE*HSTR (hand1)
    //   [epilogue] S[0..7295] = exact image of the block's 64x456 B out rows
    __shared__ __align__(16) float S[2 * TILE * HSTR];   // 33,280 B
    __shared__ float Hb[HN * 9];                         //  2,592 B

    float* const Sh0 = S;
    float* const Sh1 = S + TILE * HSTR;

    const int tid = threadIdx.x;                 // 0..63 (one wave)
    const int tilesPerRow = T / TILE;
    const int b   = blockIdx.x / tilesPerRow;
    const int t0  = (blockIdx.x - b * tilesPerRow) * TILE;
    const int t   = t0 + tid;
    const int bT0 = b * T;
    const int idx = bT0 + t;

    const float* gb = xyz + (size_t)(bT0 + t0) * NC;

    // ===== issue ALL bulk staging up front (fire-and-forget DMA) ===========
    #pragma unroll
    for (int k = 0; k < TILE; ++k)                    // hand0: coords 0..63
        dma4(gb + (size_t)k * NC + tid, Sh0 + k * HSTR);
    #pragma unroll
    for (int k = 0; k < TILE; ++k)                    // hand1: coords 63..126
        dma4(gb + (size_t)k * NC + 63 + tid, Sh1 + k * HSTR);

    // halo (small, scattered): normal loads + ds_write
    {
        const int offs[9] = {0, 1, 2, 63, 64, 65, 126, 127, 128};
        #pragma unroll
        for (int rr = 0; rr < 2; ++rr) {
            int j = tid + (rr << 6);
            if (j < HN) {
                int th = t0 - HALO + j;
                th = th < 0 ? 0 : (th > T - 1 ? T - 1 : th);
                const float* rec = xyz + (size_t)(bT0 + th) * NC;
                #pragma unroll
                for (int c = 0; c < 9; ++c)
                    Hb[j * 9 + c] = rec[offs[c]];
            }
        }
    }

    const float fg = fmask[idx];
    const float bg = bmask[idx];

    __syncthreads();   // drains DMA (vmcnt) + halo ds_writes (lgkm); 1 wave -> cheap

    float F[NF];

    // ===== temporal features from halo =====================================
    {
        auto HP = [&](int cb, int th) -> V3 {
            int j = (th - t0 + HALO) * 9 + cb;
            return V3{Hb[j], Hb[j + 1], Hb[j + 2]};
        };
        auto wvel = [&](int cb, int tt) -> V3 {
            int ta, tb; bmap(tt, T, ta, tb);
            return (HP(cb, tb) - HP(cb, ta)) * 0.5f;
        };
        auto wacc = [&](int cb, int tt) -> V3 {
            int ta, tb; bmap(tt, T, ta, tb);
            return (wvel(cb, tb) - wvel(cb, ta)) * 0.5f;
        };

        V3 velW0 = wvel(0, t), velW1 = wvel(3, t);

        { // G: velocity direction (jnp.maximum eps)
            float inv = frcp(fmaxf(norm3(velW0), 1e-6f));
            F[80] = velW0.x * inv; F[81] = velW0.y * inv; F[82] = velW0.z * inv;
        }
        {
            float inv = frcp(fmaxf(norm3(velW1), 1e-6f));
            F[83] = velW1.x * inv; F[84] = velW1.y * inv; F[85] = velW1.z * inv;
        }
        // H: velocity-turn angle (padded 0 at t = T-1)
        #pragma unroll
        for (int h = 0; h < 2; ++h) {
            float val = 0.0f;
            if (t < T - 1) {
                V3 v0 = (h == 0) ? velW0 : velW1;
                V3 v1 = wvel(h * 3, t + 1);
                V3 a  = v0 * frcp(norm3(v0) + 1e-6f);
                V3 c  = v1 * frcp(norm3(v1) + 1e-6f);
                val = acosc(dot3(a, c));
            }
            F[86 + h] = val;
        }
        // I/J: inter-hand
        V3 p0h = HP(0, t), p21h = HP(3, t);
        F[88] = dist3(p0h, p21h);
        {
            V3 rel = p21h - p0h;
            float inv = frcp(norm3(rel) + 1e-6f);
            F[89] = rel.x * inv; F[90] = rel.y * inv;
        }
        // K: d/dt of dist(wrist, nose)  (plain _norm, no eps)
        #pragma unroll
        for (int h = 0; h < 2; ++h) {
            int ta, tb; bmap(t, T, ta, tb);
            float da = norm3(HP(h * 3, ta) - HP(6, ta));
            float db = norm3(HP(h * 3, tb) - HP(6, tb));
            F[91 + h] = (db - da) * 0.5f;
        }
        // M: hand-velocity alignment
        {
            V3 ldv = velW0 * frcp(norm3(velW0) + 1e-6f);
            V3 rdv = velW1 * frcp(norm3(velW1) + 1e-6f);
            F[97] = dot3(ldv, rdv);
        }
        // N: speed
        F[98] = norm3(velW0);
        F[99] = norm3(velW1);
        // O: accel magnitude
        F[100] = norm3(wacc(0, t));
        F[101] = norm3(wacc(3, t));
        // P: proximity sigmoid
        {
            float hd = norm3(p0h - p21h);
            F[102] = frcp(1.0f + __expf(-5.0f * (0.05f - hd)));
        }
    }

    V3 p0, p21, itip0, itip1;

    // ===== per-hand features (Sh0 then Sh1; all data already resident) =====
    auto handFeats = [&](const float* R, int h, V3& wrist, V3& itip) {
        constexpr int TRI[15][3] = {
            {0, 1, 2},   {1, 2, 3},   {2, 3, 4},
            {0, 5, 6},   {5, 6, 7},   {6, 7, 8},
            {0, 9, 10},  {9, 10, 11}, {10, 11, 12},
            {0, 13, 14}, {13, 14, 15},{14, 15, 16},
            {0, 17, 18}, {17, 18, 19},{18, 19, 20}};
        auto PL = [&](int lm) -> V3 {
            int c = 3 * lm;
            return V3{R[c], R[c + 1], R[c + 2]};
        };
        // Block A: tips + curls + cross + d_ti
        V3 t_tip = PL(4),  i_tip = PL(8),  m_tip = PL(12);
        V3 r_tip = PL(16), p_tip = PL(20);
        int oa = h * 12;
        F[oa + 0] = dist3(t_tip, i_tip);
        F[oa + 1] = dist3(i_tip, m_tip);
        F[oa + 2] = dist3(m_tip, r_tip);
        F[oa + 3] = dist3(r_tip, p_tip);
        F[oa + 4] = dist3(t_tip, p_tip);
        V3 tm = PL(2),  tj = PL(3);
        F[oa + 5] = dist3(tm, t_tip) * frcp(dist3(tm, tj) + 1e-4f);
        V3 im = PL(5),  ij = PL(6);
        F[oa + 6] = dist3(im, i_tip) * frcp(dist3(im, ij) + 1e-4f);
        V3 mm = PL(9),  mj = PL(10);
        F[oa + 7] = dist3(mm, m_tip) * frcp(dist3(mm, mj) + 1e-4f);
        V3 rm = PL(13), rj = PL(14);
        F[oa + 8] = dist3(rm, r_tip) * frcp(dist3(rm, rj) + 1e-4f);
        V3 pm = PL(17), pj = PL(18);
        F[oa + 9] = dist3(pm, p_tip) * frcp(dist3(pm, pj) + 1e-4f);
        F[oa + 10] = i_tip.x - m_tip.x;
        F[oa + 11] = dist3(t_tip, im);
        // Block L: tip x-diffs
        F[93 + 2 * h + 0] = i_tip.x - m_tip.x;
        F[93 + 2 * h + 1] = m_tip.x - r_tip.x;
        itip = i_tip;
        // Block C: joint angles
        #pragma unroll
        for (int i = 0; i < 15; ++i) {
            V3 pjv = PL(TRI[i][1]);
            V3 v1 = PL(TRI[i][0]) - pjv;
            V3 v2 = PL(TRI[i][2]) - pjv;
            F[34 + h * 15 + i] = acosc(dot3(v1, v2) * frcp(norm3(v1) * norm3(v2) + 1e-6f));
        }
        // Blocks D/F: palm normal + n.up / n.fwd ; Block E: spread angles
        V3 w = PL(0);
        V3 n = cross3(PL(5) - w, PL(17) - w);
        float inv = frcp(norm3(n) + 1e-6f);
        n = n * inv;
        F[64 + 3 * h + 0] = n.x;
        F[64 + 3 * h + 1] = n.y;
        F[64 + 3 * h + 2] = n.z;
        F[76 + 2 * h + 0] = n.y;
        F[76 + 2 * h + 1] = n.z;
        V3 v5  = PL(5)  - w;
        V3 v9  = PL(9)  - w;
        V3 v13 = PL(13) - w;
        V3 v17 = PL(17) - w;
        F[70 + 3 * h + 0] = acosc(dot3(v5,  v9)  * frcp(norm3(v5)  * norm3(v9)  + 1e-6f));
        F[70 + 3 * h + 1] = acosc(dot3(v9,  v13) * frcp(norm3(v9)  * norm3(v13) + 1e-6f));
        F[70 + 3 * h + 2] = acosc(dot3(v13, v17) * frcp(norm3(v13) * norm3(v17) + 1e-6f));
        wrist = w;
    };

    handFeats(Sh0 + tid * HSTR, 0, p0, itip0);

    // Sh0 reads done -> barrier, then face DMA streams behind hand1 compute
    __syncthreads();
    {
        const float* gf = gb + 121;            // coords 121..152 (incl. face/body)
        float* Sf = Sh0;                       // reuse, rows of 33 floats
        if (tid < 32) {
            #pragma unroll
            for (int k = 0; k < TILE; ++k)     // exec-masked 32-lane DMA per record
                dma4(gf + (size_t)k * NC + tid, Sf + k * FSTR);
        }
    }

    handFeats(Sh1 + tid * HSTR, 1, p21, itip1);

    __syncthreads();   // drains face DMA

    // ===== face + body =====================================================
    {
        const float* R2 = Sh0 + tid * FSTR;
        auto FL = [&](int k) -> V3 {           // k = landmark - 42
            int c = 5 + 3 * k;                 // coord 126+3k at buffer col (126+3k)-121
            return V3{R2[c], R2[c + 1], R2[c + 2]};
        };
        V3 nose = FL(0), chin = FL(1), fore = FL(2);
        // Block B: face distances * fg
        F[24] = dist3(p0,  nose) * fg;
        F[25] = dist3(p0,  chin) * fg;
        F[26] = dist3(p0,  fore) * fg;
        F[27] = dist3(p21, nose) * fg;
        F[28] = dist3(p21, chin) * fg;
        F[29] = dist3(p21, fore) * fg;
        F[30] = dist3(itip0, nose) * fg;
        F[31] = dist3(itip0, fore) * fg;
        F[32] = dist3(itip1, nose) * fg;
        F[33] = dist3(itip1, fore) * fg;
        // Block Q: body features * bg
        V3 lsh = FL(3), rsh = FL(4);
        V3 shmid = (lsh + rsh) * 0.5f;
        float shw = dist3(lsh, rsh);
        float invw = frcp(shw + 1e-6f);
        F[103] = (p0.y  - shmid.y) * invw * bg;
        F[104] = (p0.x  - shmid.x) * invw * bg;
        F[105] = dist3(p0, lsh) * bg;
        F[106] = dist3(p0, FL(5)) * bg;
        F[107] = (p21.y - shmid.y) * invw * bg;
        F[108] = (p21.x - shmid.x) * invw * bg;
        F[109] = dist3(p21, rsh) * bg;
        F[110] = dist3(p21, FL(6)) * bg;
        F[111] = shw * bg;
        V3 mouth = (FL(7) + FL(8)) * 0.5f;
        F[112] = dist3(p0,  mouth) * bg;
        F[113] = dist3(p21, mouth) * bg;
    }

    // ===== epilogue: stage F as exact out-image in LDS, burst dwordx4 store =
    // Old path: 57 float2 stores/lane at 456 B lane stride = 64 lines touched
    // per instruction (~3650 line transactions/block) + partial-line RMW
    // (WRITE_SIZE 91 MB vs 58.4 MB ideal). New path: full-line coalesced.
    __syncthreads();                       // all S reads (hand1 + face rows) done
    {
        float* W = S + tid * NF;           // image row tid (456 B, 8 B aligned)
        #pragma unroll
        for (int f = 0; f < NF; f += 2) {  // 57 ds_write_b64 (4-way conflict, tiny)
            float2 v; v.x = F[f]; v.y = F[f + 1];
            *reinterpret_cast<float2*>(W + f) = v;
        }
    }
    __syncthreads();                       // image complete
    {
        // 64 rows x 456 B = 29,184 B = 1824 float4 = 28*64 + 32
        float* dst = out + (size_t)(bT0 + t0) * NF;   // 16 B aligned (456*64 % 16 == 0)
        #pragma unroll
        for (int i = 0; i < 28; ++i) {
            const int o4 = (i * 64 + tid) * 4;
            float4 v = *reinterpret_cast<const float4*>(S + o4);
            *reinterpret_cast<float4*>(dst + o4) = v;
        }
        if (tid < 32) {
            const int o4 = (28 * 64 + tid) * 4;
            float4 v = *reinterpret_cast<const float4*>(S + o4);
            *reinterpret_cast<float4*>(dst + o4) = v;
        }
    }
}

// ---------------------------------------------------------------------------
// Fallback: direct kernel (correct for any shape)
// ---------------------------------------------------------------------------
__constant__ int c_TRI[15][3] = {
    {0, 1, 2},   {1, 2, 3},   {2, 3, 4},
    {0, 5, 6},   {5, 6, 7},   {6, 7, 8},
    {0, 9, 10},  {9, 10, 11}, {10, 11, 12},
    {0, 13, 14}, {13, 14, 15},{14, 15, 16},
    {0, 17, 18}, {17, 18, 19},{18, 19, 20}};

__global__ __launch_bounds__(256) void geo_direct(
    const float* __restrict__ xyz,
    const float* __restrict__ fmask,
    const float* __restrict__ bmask,
    float* __restrict__ out,
    int BT, int T)
{
    int idx = blockIdx.x * blockDim.x + threadIdx.x;
    if (idx >= BT) return;
    int b = idx / T;
    int t = idx - b * T;
    int bT0 = b * T;

    auto ldp = [&](int tt, int lm) -> V3 {
        const float* p = xyz + ((size_t)(bT0 + tt) * 51 + (size_t)lm) * 3;
        return V3{p[0], p[1], p[2]};
    };
    auto P = [&](int lm) -> V3 { return ldp(t, lm); };
    auto velAt = [&](int lm, int tt) -> V3 {
        int ta, tb; bmap(tt, T, ta, tb);
        return (ldp(tb, lm) - ldp(ta, lm)) * 0.5f;
    };
    auto accAt = [&](int lm, int tt) -> V3 {
        int ta, tb; bmap(tt, T, ta, tb);
        return (velAt(lm, tb) - velAt(lm, ta)) * 0.5f;
    };

    float fg = fmask[idx];
    float bg = bmask[idx];
    float* o = out + (size_t)idx * NF;

    for (int h = 0; h < 2; ++h) {
        int base = h * 21;
        V3 t_tip = P(base + 4),  i_tip = P(base + 8),  m_tip = P(base + 12);
        V3 r_tip = P(base + 16), p_tip = P(base + 20);
        float* oa = o + h * 12;
        oa[0] = dist3(t_tip, i_tip);
        oa[1] = dist3(i_tip, m_tip);
        oa[2] = dist3(m_tip, r_tip);
        oa[3] = dist3(r_tip, p_tip);
        oa[4] = dist3(t_tip, p_tip);
        V3 tm = P(base + 2),  tj = P(base + 3);
        oa[5] = dist3(tm, t_tip) / (dist3(tm, tj) + 1e-4f);
        V3 im = P(base + 5),  ij = P(base + 6);
        oa[6] = dist3(im, i_tip) / (dist3(im, ij) + 1e-4f);
        V3 mm = P(base + 9),  mj = P(base + 10);
        oa[7] = dist3(mm, m_tip) / (dist3(mm, mj) + 1e-4f);
        V3 rm = P(base + 13), rj = P(base + 14);
        oa[8] = dist3(rm, r_tip) / (dist3(rm, rj) + 1e-4f);
        V3 pm = P(base + 17), pj = P(base + 18);
        oa[9] = dist3(pm, p_tip) / (dist3(pm, pj) + 1e-4f);
        oa[10] = i_tip.x - m_tip.x;
        oa[11] = dist3(t_tip, im);
    }

    V3 p0 = P(0), p21 = P(21);
    V3 nose = P(42), chin = P(43), fore = P(44);
    V3 itip0 = P(8), itip1 = P(29);
    o[24] = dist3(p0, nose) * fg;
    o[25] = dist3(p0, chin) * fg;
    o[26] = dist3(p0, fore) * fg;
    o[27] = dist3(p21, nose) * fg;
    o[28] = dist3(p21, chin) * fg;
    o[29] = dist3(p21, fore) * fg;
    o[30] = dist3(itip0, nose) * fg;
    o[31] = dist3(itip0, fore) * fg;
    o[32] = dist3(itip1, nose) * fg;
    o[33] = dist3(itip1, fore) * fg;

    for (int h = 0; h < 2; ++h) {
        int base = h * 21;
        for (int i = 0; i < 15; ++i) {
            V3 pj = P(base + c_TRI[i][1]);
            V3 v1 = P(base + c_TRI[i][0]) - pj;
            V3 v2 = P(base + c_TRI[i][2]) - pj;
            o[34 + h * 15 + i] = acosc(dot3(v1, v2) / (norm3(v1) * norm3(v2) + 1e-6f));
        }
    }

    V3 nrm[2];
    for (int h = 0; h < 2; ++h) {
        int base = h * 21;
        V3 w = (h == 0) ? p0 : p21;
        V3 n = cross3(P(base + 5) - w, P(base + 17) - w);
        float inv = 1.0f / (norm3(n) + 1e-6f);
        n = n * inv;
        nrm[h] = n;
        o[64 + 3 * h + 0] = n.x;
        o[64 + 3 * h + 1] = n.y;
        o[64 + 3 * h + 2] = n.z;
    }

    for (int h = 0; h < 2; ++h) {
        int base = h * 21;
        V3 w = (h == 0) ? p0 : p21;
        V3 v5  = P(base + 5)  - w;
        V3 v9  = P(base + 9)  - w;
        V3 v13 = P(base + 13) - w;
        V3 v17 = P(base + 17) - w;
        o[70 + 3 * h + 0] = acosc(dot3(v5,  v9)  / (norm3(v5)  * norm3(v9)  + 1e-6f));
        o[70 + 3 * h + 1] = acosc(dot3(v9,  v13) / (norm3(v9)  * norm3(v13) + 1e-6f));
        o[70 + 3 * h + 2] = acosc(dot3(v13, v17) / (norm3(v13) * norm3(v17) + 1e-6f));
    }

    for (int h = 0; h < 2; ++h) {
        o[76 + 2 * h + 0] = nrm[h].y;
        o[76 + 2 * h + 1] = nrm[h].z;
    }

    V3 velW[2];
    for (int h = 0; h < 2; ++h) {
        V3 v = velAt(h * 21, t);
        velW[h] = v;
        float inv = 1.0f / fmaxf(norm3(v), 1e-6f);
        o[80 + 3 * h + 0] = v.x * inv;
        o[80 + 3 * h + 1] = v.y * inv;
        o[80 + 3 * h + 2] = v.z * inv;
    }

    for (int h = 0; h < 2; ++h) {
        float val = 0.0f;
        if (t < T - 1) {
            V3 v0 = velW[h];
            V3 v1 = velAt(h * 21, t + 1);
            V3 a = v0 * (1.0f / (norm3(v0) + 1e-6f));
            V3 c = v1 * (1.0f / (norm3(v1) + 1e-6f));
            val = acosc(dot3(a, c));
        }
        o[86 + h] = val;
    }

    o[88] = dist3(p0, p21);
    {
        V3 rel = p21 - p0;
        float inv = 1.0f / (norm3(rel) + 1e-6f);
        o[89] = rel.x * inv;
        o[90] = rel.y * inv;
    }

    for (int h = 0; h < 2; ++h) {
        int lm = h * 21;
        int ta, tb; bmap(t, T, ta, tb);
        float da = norm3(ldp(ta, lm) - ldp(ta, 42));
        float db = norm3(ldp(tb, lm) - ldp(tb, 42));
        o[91 + h] = (db - da) * 0.5f;
    }

    for (int h = 0; h < 2; ++h) {
        int base = h * 21;
        float ix = P(base + 8).x, mx = P(base + 12).x, rx = P(base + 16).x;
        o[93 + 2 * h + 0] = ix - mx;
        o[93 + 2 * h + 1] = mx - rx;
    }

    {
        V3 ldv = velW[0] * (1.0f / (norm3(velW[0]) + 1e-6f));
        V3 rdv = velW[1] * (1.0f / (norm3(velW[1]) + 1e-6f));
        o[97] = dot3(ldv, rdv);
    }

    o[98] = norm3(velW[0]);
    o[99] = norm3(velW[1]);
    o[100] = norm3(accAt(0, t));
    o[101] = norm3(accAt(21, t));

    {
        float hd = norm3(p0 - p21);
        o[102] = 1.0f / (1.0f + expf(-5.0f * (0.05f - hd)));
    }

    {
        V3 lsh = P(45), rsh = P(46);
        V3 shmid = (lsh + rsh) * 0.5f;
        float shw = dist3(lsh, rsh);
        float invw = 1.0f / (shw + 1e-6f);
        o[103] = (p0.y - shmid.y) * invw * bg;
        o[104] = (p0.x - shmid.x) * invw * bg;
        o[105] = dist3(p0, lsh) * bg;
        o[106] = dist3(p0, P(47)) * bg;
        o[107] = (p21.y - shmid.y) * invw * bg;
        o[108] = (p21.x - shmid.x) * invw * bg;
        o[109] = dist3(p21, rsh) * bg;
        o[110] = dist3(p21, P(48)) * bg;
        o[111] = shw * bg;
        V3 mouth = (P(49) + P(50)) * 0.5f;
        o[112] = dist3(p0, mouth) * bg;
        o[113] = dist3(p21, mouth) * bg;
    }
}

extern "C" void kernel_launch(void* const* d_in, const int* in_sizes, int n_in,
                              void* d_out, int out_size, void* d_ws, size_t ws_size,
                              hipStream_t stream) {
    const float* xyz   = (const float*)d_in[0];
    const float* fmask = (const float*)d_in[1];
    const float* bmask = (const float*)d_in[2];
    float* out = (float*)d_out;

    const int BT = in_sizes[1];   // B*T (face_mask element count)
    const int T  = 512;           // per reference setup_inputs

    if (T % TILE == 0 && BT % T == 0 && T >= 3 * TILE) {
        // 2048 one-wave blocks; LDS 35.9 KB -> 4 resident/CU
        geo_fused<<<BT / TILE, TILE, 0, stream>>>(xyz, fmask, bmask, out, T);
    } else {
        const int threads = 256;
        geo_direct<<<(BT + threads - 1) / threads, threads, 0, stream>>>(
            xyz, fmask, bmask, out, BT, T);
    }
}

// Round 2
// 149.750 us; speedup vs baseline: 1.0874x; 1.0178x over previous
//
#include <hip/hip_runtime.h>
#include <math.h>

// ---------------------------------------------------------------------------
// GeoFeatureExtractor: B=256, T=512, N=51 landmarks x 3 (fp32), 114 features.
// Round 7: occupancy play. Counters showed Occupancy 9% (4 blocks/CU, 1
// wave/SIMD -> zero TLP), VALUBusy 12.6%, HBM 25% -> pure exposed latency.
// Change: ONE staging buffer (64x65 = 16.6 KB) reused by hand0 -> hand1 ->
// face -> out-image (in 32-row halves), + halo = 19.2 KB LDS -> 8 blocks/CU
// (2 waves/SIMD). Phases serialize inside a block; cross-block TLP hides the
// drains. Halo loads issued BEFORE hand0 DMA so their waitcnt doesn't drain
// the DMA queue; temporal features (Hb-only) run under DMA flight via a
// manual lgkmcnt-only wait.
// Round 6 win kept: LDS out-image + coalesced dwordx4 burst store
// (WRITE_SIZE 91 -> 58.4 MB ideal). Hastings acos, __expf, v_rcp/v_sqrt.
// ---------------------------------------------------------------------------

#define NF   114
#define NC   153
#define TILE 64
#define HSTR 65                 // hand stage stride (odd -> conflict-free reads)
#define FSTR 33                 // face stage stride (odd)
#define HALO 4
#define HN   (TILE + 2 * HALO)  // 72 halo timesteps

#if defined(__has_builtin)
#if __has_builtin(__builtin_amdgcn_global_load_lds)
#define USE_DMA 1
#endif
#endif
#ifndef USE_DMA
#define USE_DMA 0
#endif

typedef const __attribute__((address_space(1))) void gas_t;
typedef __attribute__((address_space(3))) void las_t;

// per-lane global addr g; LDS dest = uniform base `lds` + lane*4 (exec-masked)
__device__ __forceinline__ void dma4(const float* g, float* lds) {
#if USE_DMA
    __builtin_amdgcn_global_load_lds((gas_t*)g, (las_t*)lds, 4, 0, 0);
#else
    lds[threadIdx.x & 63] = *g;
#endif
}

struct V3 { float x, y, z; };

__device__ __forceinline__ V3 operator-(V3 a, V3 b) { return {a.x - b.x, a.y - b.y, a.z - b.z}; }
__device__ __forceinline__ V3 operator+(V3 a, V3 b) { return {a.x + b.x, a.y + b.y, a.z + b.z}; }
__device__ __forceinline__ V3 operator*(V3 a, float s) { return {a.x * s, a.y * s, a.z * s}; }
__device__ __forceinline__ float dot3(V3 a, V3 b) { return a.x * b.x + a.y * b.y + a.z * b.z; }
__device__ __forceinline__ V3 cross3(V3 a, V3 b) {
    return {a.y * b.z - a.z * b.y, a.z * b.x - a.x * b.z, a.x * b.y - a.y * b.x};
}

__device__ __forceinline__ float fsqrt(float x) { return __builtin_amdgcn_sqrtf(x); }
__device__ __forceinline__ float frcp(float x)  { return __builtin_amdgcn_rcpf(x); }

__device__ __forceinline__ float norm3(V3 a) { return fsqrt(dot3(a, a)); }
__device__ __forceinline__ float dist3(V3 a, V3 b) { V3 d = a - b; return fsqrt(dot3(d, d) + 1e-6f); }

// clip + Hastings acos approximation, |err| < 7e-5 rad
__device__ __forceinline__ float acosc(float c) {
    c = fminf(fmaxf(c, -1.0f + 1e-6f), 1.0f - 1e-6f);
    float ax = fabsf(c);
    float r = fsqrt(1.0f - ax) *
              (1.5707288f + ax * (-0.2121144f + ax * (0.0742610f - 0.0187293f * ax)));
    return c < 0.0f ? 3.14159265358979f - r : r;
}

// boundary-mapped central-diff endpoints (exact _cdiff semantics)
__device__ __forceinline__ void bmap(int tt, int T, int& ta, int& tb) {
    if (tt == 0)          { ta = 0;      tb = 2;     }
    else if (tt == T - 1) { ta = T - 3;  tb = T - 1; }
    else                  { ta = tt - 1; tb = tt + 1; }
}

__global__ __launch_bounds__(64, 2) void geo_fused(
    const float* __restrict__ xyz,
    const float* __restrict__ fmask,
    const float* __restrict__ bmask,
    float* __restrict__ out,
    int T)
{
    // Single union buffer, phases overlay it sequentially:
    //   hand0 stage (64x65) -> hand1 stage (64x65) -> face stage (64x33)
    //   -> out-image half A (32x114) -> out-image half B (32x114)
    __shared__ __align__(16) float S[TILE * HSTR];   // 16,640 B
    __shared__ float Hb[HN * 9];                     //  2,592 B  => 19.2 KB total

    const int tid = threadIdx.x;                 // 0..63 (one wave)
    const int tilesPerRow = T / TILE;
    const int b   = blockIdx.x / tilesPerRow;
    const int t0  = (blockIdx.x - b * tilesPerRow) * TILE;
    const int t   = t0 + tid;
    const int bT0 = b * T;
    const int idx = bT0 + t;

    const float* gb = xyz + (size_t)(bT0 + t0) * NC;

    // ===== phase 0: halo loads (FIRST, so their wait doesn't drain the DMA
    // queue), then hand0 DMA, then halo ds_writes ==========================
    const int offs[9] = {0, 1, 2, 63, 64, 65, 126, 127, 128};
    float hreg0[9], hreg1[9];
    {
        int th0 = t0 - HALO + tid;
        th0 = th0 < 0 ? 0 : (th0 > T - 1 ? T - 1 : th0);
        const float* rec = xyz + (size_t)(bT0 + th0) * NC;
        #pragma unroll
        for (int c = 0; c < 9; ++c) hreg0[c] = rec[offs[c]];
    }
    {
        int j = tid + 64;
        if (j < HN) {
            int th1 = t0 - HALO + j;
            th1 = th1 > T - 1 ? T - 1 : th1;
            const float* rec = xyz + (size_t)(bT0 + th1) * NC;
            #pragma unroll
            for (int c = 0; c < 9; ++c) hreg1[c] = rec[offs[c]];
        }
    }
    const float fg = fmask[idx];
    const float bg = bmask[idx];

    #pragma unroll
    for (int k = 0; k < TILE; ++k)                    // hand0: coords 0..63
        dma4(gb + (size_t)k * NC + tid, S + k * HSTR);

    {
        #pragma unroll
        for (int c = 0; c < 9; ++c) Hb[tid * 9 + c] = hreg0[c];
        int j = tid + 64;
        if (j < HN) {
            #pragma unroll
            for (int c = 0; c < 9; ++c) Hb[j * 9 + c] = hreg1[c];
        }
    }

    float F[NF];

    // halo visible (lgkm only) -> temporal features run UNDER hand0 DMA flight
    asm volatile("s_waitcnt lgkmcnt(0)" ::: "memory");

    // ===== temporal features from halo (Hb only) ===========================
    {
        auto HP = [&](int cb, int th) -> V3 {
            int j = (th - t0 + HALO) * 9 + cb;
            return V3{Hb[j], Hb[j + 1], Hb[j + 2]};
        };
        auto wvel = [&](int cb, int tt) -> V3 {
            int ta, tb; bmap(tt, T, ta, tb);
            return (HP(cb, tb) - HP(cb, ta)) * 0.5f;
        };
        auto wacc = [&](int cb, int tt) -> V3 {
            int ta, tb; bmap(tt, T, ta, tb);
            return (wvel(cb, tb) - wvel(cb, ta)) * 0.5f;
        };

        V3 velW0 = wvel(0, t), velW1 = wvel(3, t);

        { // G: velocity direction (jnp.maximum eps)
            float inv = frcp(fmaxf(norm3(velW0), 1e-6f));
            F[80] = velW0.x * inv; F[81] = velW0.y * inv; F[82] = velW0.z * inv;
        }
        {
            float inv = frcp(fmaxf(norm3(velW1), 1e-6f));
            F[83] = velW1.x * inv; F[84] = velW1.y * inv; F[85] = velW1.z * inv;
        }
        // H: velocity-turn angle (padded 0 at t = T-1)
        #pragma unroll
        for (int h = 0; h < 2; ++h) {
            float val = 0.0f;
            if (t < T - 1) {
                V3 v0 = (h == 0) ? velW0 : velW1;
                V3 v1 = wvel(h * 3, t + 1);
                V3 a  = v0 * frcp(norm3(v0) + 1e-6f);
                V3 c  = v1 * frcp(norm3(v1) + 1e-6f);
                val = acosc(dot3(a, c));
            }
            F[86 + h] = val;
        }
        // I/J: inter-hand
        V3 p0h = HP(0, t), p21h = HP(3, t);
        F[88] = dist3(p0h, p21h);
        {
            V3 rel = p21h - p0h;
            float inv = frcp(norm3(rel) + 1e-6f);
            F[89] = rel.x * inv; F[90] = rel.y * inv;
        }
        // K: d/dt of dist(wrist, nose)  (plain _norm, no eps)
        #pragma unroll
        for (int h = 0; h < 2; ++h) {
            int ta, tb; bmap(t, T, ta, tb);
            float da = norm3(HP(h * 3, ta) - HP(6, ta));
            float db = norm3(HP(h * 3, tb) - HP(6, tb));
            F[91 + h] = (db - da) * 0.5f;
        }
        // M: hand-velocity alignment
        {
            V3 ldv = velW0 * frcp(norm3(velW0) + 1e-6f);
            V3 rdv = velW1 * frcp(norm3(velW1) + 1e-6f);
            F[97] = dot3(ldv, rdv);
        }
        // N: speed
        F[98] = norm3(velW0);
        F[99] = norm3(velW1);
        // O: accel magnitude
        F[100] = norm3(wacc(0, t));
        F[101] = norm3(wacc(3, t));
        // P: proximity sigmoid
        {
            float hd = norm3(p0h - p21h);
            F[102] = frcp(1.0f + __expf(-5.0f * (0.05f - hd)));
        }
    }

    V3 p0, p21, itip0, itip1;

    auto handFeats = [&](const float* R, int h, V3& wrist, V3& itip) {
        constexpr int TRI[15][3] = {
            {0, 1, 2},   {1, 2, 3},   {2, 3, 4},
            {0, 5, 6},   {5, 6, 7},   {6, 7, 8},
            {0, 9, 10},  {9, 10, 11}, {10, 11, 12},
            {0, 13, 14}, {13, 14, 15},{14, 15, 16},
            {0, 17, 18}, {17, 18, 19},{18, 19, 20}};
        auto PL = [&](int lm) -> V3 {
            int c = 3 * lm;
            return V3{R[c], R[c + 1], R[c + 2]};
        };
        // Block A: tips + curls + cross + d_ti
        V3 t_tip = PL(4),  i_tip = PL(8),  m_tip = PL(12);
        V3 r_tip = PL(16), p_tip = PL(20);
        int oa = h * 12;
        F[oa + 0] = dist3(t_tip, i_tip);
        F[oa + 1] = dist3(i_tip, m_tip);
        F[oa + 2] = dist3(m_tip, r_tip);
        F[oa + 3] = dist3(r_tip, p_tip);
        F[oa + 4] = dist3(t_tip, p_tip);
        V3 tm = PL(2),  tj = PL(3);
        F[oa + 5] = dist3(tm, t_tip) * frcp(dist3(tm, tj) + 1e-4f);
        V3 im = PL(5),  ij = PL(6);
        F[oa + 6] = dist3(im, i_tip) * frcp(dist3(im, ij) + 1e-4f);
        V3 mm = PL(9),  mj = PL(10);
        F[oa + 7] = dist3(mm, m_tip) * frcp(dist3(mm, mj) + 1e-4f);
        V3 rm = PL(13), rj = PL(14);
        F[oa + 8] = dist3(rm, r_tip) * frcp(dist3(rm, rj) + 1e-4f);
        V3 pm = PL(17), pj = PL(18);
        F[oa + 9] = dist3(pm, p_tip) * frcp(dist3(pm, pj) + 1e-4f);
        F[oa + 10] = i_tip.x - m_tip.x;
        F[oa + 11] = dist3(t_tip, im);
        // Block L: tip x-diffs
        F[93 + 2 * h + 0] = i_tip.x - m_tip.x;
        F[93 + 2 * h + 1] = m_tip.x - r_tip.x;
        itip = i_tip;
        // Block C: joint angles
        #pragma unroll
        for (int i = 0; i < 15; ++i) {
            V3 pjv = PL(TRI[i][1]);
            V3 v1 = PL(TRI[i][0]) - pjv;
            V3 v2 = PL(TRI[i][2]) - pjv;
            F[34 + h * 15 + i] = acosc(dot3(v1, v2) * frcp(norm3(v1) * norm3(v2) + 1e-6f));
        }
        // Blocks D/F: palm normal + n.up / n.fwd ; Block E: spread angles
        V3 w = PL(0);
        V3 n = cross3(PL(5) - w, PL(17) - w);
        float inv = frcp(norm3(n) + 1e-6f);
        n = n * inv;
        F[64 + 3 * h + 0] = n.x;
        F[64 + 3 * h + 1] = n.y;
        F[64 + 3 * h + 2] = n.z;
        F[76 + 2 * h + 0] = n.y;
        F[76 + 2 * h + 1] = n.z;
        V3 v5  = PL(5)  - w;
        V3 v9  = PL(9)  - w;
        V3 v13 = PL(13) - w;
        V3 v17 = PL(17) - w;
        F[70 + 3 * h + 0] = acosc(dot3(v5,  v9)  * frcp(norm3(v5)  * norm3(v9)  + 1e-6f));
        F[70 + 3 * h + 1] = acosc(dot3(v9,  v13) * frcp(norm3(v9)  * norm3(v13) + 1e-6f));
        F[70 + 3 * h + 2] = acosc(dot3(v13, v17) * frcp(norm3(v13) * norm3(v17) + 1e-6f));
        wrist = w;
    };

    // hand0 data arrived (also waits masks; temporal compute covered flight)
    asm volatile("s_waitcnt vmcnt(0)" ::: "memory");
    __builtin_amdgcn_sched_barrier(0);

    handFeats(S + tid * HSTR, 0, p0, itip0);

    __syncthreads();   // S reads retired before overwrite

    // ===== phase 1: hand1 DMA into the SAME buffer =========================
    #pragma unroll
    for (int k = 0; k < TILE; ++k)                    // hand1: coords 63..126
        dma4(gb + (size_t)k * NC + 63 + tid, S + k * HSTR);

    __syncthreads();   // drain hand1 DMA

    handFeats(S + tid * HSTR, 1, p21, itip1);

    __syncthreads();   // S reads retired before overwrite

    // ===== phase 2: face DMA (32 lanes) into the SAME buffer ===============
    {
        const float* gf = gb + 121;            // coords 121..152
        if (tid < 32) {
            #pragma unroll
            for (int k = 0; k < TILE; ++k)
                dma4(gf + (size_t)k * NC + tid, S + k * FSTR);
        }
    }

    __syncthreads();   // drain face DMA

    // ===== face + body =====================================================
    {
        const float* R2 = S + tid * FSTR;
        auto FL = [&](int k) -> V3 {           // k = landmark - 42
            int c = 5 + 3 * k;                 // coord 126+3k at col (126+3k)-121
            return V3{R2[c], R2[c + 1], R2[c + 2]};
        };
        V3 nose = FL(0), chin = FL(1), fore = FL(2);
        // Block B: face distances * fg
        F[24] = dist3(p0,  nose) * fg;
        F[25] = dist3(p0,  chin) * fg;
        F[26] = dist3(p0,  fore) * fg;
        F[27] = dist3(p21, nose) * fg;
        F[28] = dist3(p21, chin) * fg;
        F[29] = dist3(p21, fore) * fg;
        F[30] = dist3(itip0, nose) * fg;
        F[31] = dist3(itip0, fore) * fg;
        F[32] = dist3(itip1, nose) * fg;
        F[33] = dist3(itip1, fore) * fg;
        // Block Q: body features * bg
        V3 lsh = FL(3), rsh = FL(4);
        V3 shmid = (lsh + rsh) * 0.5f;
        float shw = dist3(lsh, rsh);
        float invw = frcp(shw + 1e-6f);
        F[103] = (p0.y  - shmid.y) * invw * bg;
        F[104] = (p0.x  - shmid.x) * invw * bg;
        F[105] = dist3(p0, lsh) * bg;
        F[106] = dist3(p0, FL(5)) * bg;
        F[107] = (p21.y - shmid.y) * invw * bg;
        F[108] = (p21.x - shmid.x) * invw * bg;
        F[109] = dist3(p21, rsh) * bg;
        F[110] = dist3(p21, FL(6)) * bg;
        F[111] = shw * bg;
        V3 mouth = (FL(7) + FL(8)) * 0.5f;
        F[112] = dist3(p0,  mouth) * bg;
        F[113] = dist3(p21, mouth) * bg;
    }

    // ===== epilogue: out-image in 32-row halves, coalesced dwordx4 burst ===
    // half = 32 rows x 456 B = 14,592 B = 912 float4 = 14*64 + 16
    float* dst = out + (size_t)(bT0 + t0) * NF;

    __syncthreads();                       // face reads of S retired
    if (tid < 32) {                        // image rows 0..31
        float* W = S + tid * NF;
        #pragma unroll
        for (int f = 0; f < NF; f += 2) {
            float2 v; v.x = F[f]; v.y = F[f + 1];
            *reinterpret_cast<float2*>(W + f) = v;
        }
    }
    __syncthreads();
    #pragma unroll
    for (int i = 0; i < 14; ++i) {
        const int o4 = (i * 64 + tid) * 4;
        float4 v = *reinterpret_cast<const float4*>(S + o4);
        *reinterpret_cast<float4*>(dst + o4) = v;
    }
    if (tid < 16) {
        const int o4 = (14 * 64 + tid) * 4;
        float4 v = *reinterpret_cast<const float4*>(S + o4);
        *reinterpret_cast<float4*>(dst + o4) = v;
    }
    __syncthreads();                       // half-A copy reads retired
    if (tid >= 32) {                       // image rows 32..63
        float* W = S + (tid - 32) * NF;
        #pragma unroll
        for (int f = 0; f < NF; f += 2) {
            float2 v; v.x = F[f]; v.y = F[f + 1];
            *reinterpret_cast<float2*>(W + f) = v;
        }
    }
    __syncthreads();
    {
        float* dst2 = dst + 32 * NF;
        #pragma unroll
        for (int i = 0; i < 14; ++i) {
            const int o4 = (i * 64 + tid) * 4;
            float4 v = *reinterpret_cast<const float4*>(S + o4);
            *reinterpret_cast<float4*>(dst2 + o4) = v;
        }
        if (tid < 16) {
            const int o4 = (14 * 64 + tid) * 4;
            float4 v = *reinterpret_cast<const float4*>(S + o4);
            *reinterpret_cast<float4*>(dst2 + o4) = v;
        }
    }
}

// ---------------------------------------------------------------------------
// Fallback: direct kernel (correct for any shape)
// ---------------------------------------------------------------------------
__constant__ int c_TRI[15][3] = {
    {0, 1, 2},   {1, 2, 3},   {2, 3, 4},
    {0, 5, 6},   {5, 6, 7},   {6, 7, 8},
    {0, 9, 10},  {9, 10, 11}, {10, 11, 12},
    {0, 13, 14}, {13, 14, 15},{14, 15, 16},
    {0, 17, 18}, {17, 18, 19},{18, 19, 20}};

__global__ __launch_bounds__(256) void geo_direct(
    const float* __restrict__ xyz,
    const float* __restrict__ fmask,
    const float* __restrict__ bmask,
    float* __restrict__ out,
    int BT, int T)
{
    int idx = blockIdx.x * blockDim.x + threadIdx.x;
    if (idx >= BT) return;
    int b = idx / T;
    int t = idx - b * T;
    int bT0 = b * T;

    auto ldp = [&](int tt, int lm) -> V3 {
        const float* p = xyz + ((size_t)(bT0 + tt) * 51 + (size_t)lm) * 3;
        return V3{p[0], p[1], p[2]};
    };
    auto P = [&](int lm) -> V3 { return ldp(t, lm); };
    auto velAt = [&](int lm, int tt) -> V3 {
        int ta, tb; bmap(tt, T, ta, tb);
        return (ldp(tb, lm) - ldp(ta, lm)) * 0.5f;
    };
    auto accAt = [&](int lm, int tt) -> V3 {
        int ta, tb; bmap(tt, T, ta, tb);
        return (velAt(lm, tb) - velAt(lm, ta)) * 0.5f;
    };

    float fg = fmask[idx];
    float bg = bmask[idx];
    float* o = out + (size_t)idx * NF;

    for (int h = 0; h < 2; ++h) {
        int base = h * 21;
        V3 t_tip = P(base + 4),  i_tip = P(base + 8),  m_tip = P(base + 12);
        V3 r_tip = P(base + 16), p_tip = P(base + 20);
        float* oa = o + h * 12;
        oa[0] = dist3(t_tip, i_tip);
        oa[1] = dist3(i_tip, m_tip);
        oa[2] = dist3(m_tip, r_tip);
        oa[3] = dist3(r_tip, p_tip);
        oa[4] = dist3(t_tip, p_tip);
        V3 tm = P(base + 2),  tj = P(base + 3);
        oa[5] = dist3(tm, t_tip) / (dist3(tm, tj) + 1e-4f);
        V3 im = P(base + 5),  ij = P(base + 6);
        oa[6] = dist3(im, i_tip) / (dist3(im, ij) + 1e-4f);
        V3 mm = P(base + 9),  mj = P(base + 10);
        oa[7] = dist3(mm, m_tip) / (dist3(mm, mj) + 1e-4f);
        V3 rm = P(base + 13), rj = P(base + 14);
        oa[8] = dist3(rm, r_tip) / (dist3(rm, rj) + 1e-4f);
        V3 pm = P(base + 17), pj = P(base + 18);
        oa[9] = dist3(pm, p_tip) / (dist3(pm, pj) + 1e-4f);
        oa[10] = i_tip.x - m_tip.x;
        oa[11] = dist3(t_tip, im);
    }

    V3 p0 = P(0), p21 = P(21);
    V3 nose = P(42), chin = P(43), fore = P(44);
    V3 itip0 = P(8), itip1 = P(29);
    o[24] = dist3(p0, nose) * fg;
    o[25] = dist3(p0, chin) * fg;
    o[26] = dist3(p0, fore) * fg;
    o[27] = dist3(p21, nose) * fg;
    o[28] = dist3(p21, chin) * fg;
    o[29] = dist3(p21, fore) * fg;
    o[30] = dist3(itip0, nose) * fg;
    o[31] = dist3(itip0, fore) * fg;
    o[32] = dist3(itip1, nose) * fg;
    o[33] = dist3(itip1, fore) * fg;

    for (int h = 0; h < 2; ++h) {
        int base = h * 21;
        for (int i = 0; i < 15; ++i) {
            V3 pj = P(base + c_TRI[i][1]);
            V3 v1 = P(base + c_TRI[i][0]) - pj;
            V3 v2 = P(base + c_TRI[i][2]) - pj;
            o[34 + h * 15 + i] = acosc(dot3(v1, v2) / (norm3(v1) * norm3(v2) + 1e-6f));
        }
    }

    V3 nrm[2];
    for (int h = 0; h < 2; ++h) {
        int base = h * 21;
        V3 w = (h == 0) ? p0 : p21;
        V3 n = cross3(P(base + 5) - w, P(base + 17) - w);
        float inv = 1.0f / (norm3(n) + 1e-6f);
        n = n * inv;
        nrm[h] = n;
        o[64 + 3 * h + 0] = n.x;
        o[64 + 3 * h + 1] = n.y;
        o[64 + 3 * h + 2] = n.z;
    }

    for (int h = 0; h < 2; ++h) {
        int base = h * 21;
        V3 w = (h == 0) ? p0 : p21;
        V3 v5  = P(base + 5)  - w;
        V3 v9  = P(base + 9)  - w;
        V3 v13 = P(base + 13) - w;
        V3 v17 = P(base + 17) - w;
        o[70 + 3 * h + 0] = acosc(dot3(v5,  v9)  / (norm3(v5)  * norm3(v9)  + 1e-6f));
        o[70 + 3 * h + 1] = acosc(dot3(v9,  v13) / (norm3(v9)  * norm3(v13) + 1e-6f));
        o[70 + 3 * h + 2] = acosc(dot3(v13, v17) / (norm3(v13) * norm3(v17) + 1e-6f));
    }

    for (int h = 0; h < 2; ++h) {
        o[76 + 2 * h + 0] = nrm[h].y;
        o[76 + 2 * h + 1] = nrm[h].z;
    }

    V3 velW[2];
    for (int h = 0; h < 2; ++h) {
        V3 v = velAt(h * 21, t);
        velW[h] = v;
        float inv = 1.0f / fmaxf(norm3(v), 1e-6f);
        o[80 + 3 * h + 0] = v.x * inv;
        o[80 + 3 * h + 1] = v.y * inv;
        o[80 + 3 * h + 2] = v.z * inv;
    }

    for (int h = 0; h < 2; ++h) {
        float val = 0.0f;
        if (t < T - 1) {
            V3 v0 = velW[h];
            V3 v1 = velAt(h * 21, t + 1);
            V3 a = v0 * (1.0f / (norm3(v0) + 1e-6f));
            V3 c = v1 * (1.0f / (norm3(v1) + 1e-6f));
            val = acosc(dot3(a, c));
        }
        o[86 + h] = val;
    }

    o[88] = dist3(p0, p21);
    {
        V3 rel = p21 - p0;
        float inv = 1.0f / (norm3(rel) + 1e-6f);
        o[89] = rel.x * inv;
        o[90] = rel.y * inv;
    }

    for (int h = 0; h < 2; ++h) {
        int lm = h * 21;
        int ta, tb; bmap(t, T, ta, tb);
        float da = norm3(ldp(ta, lm) - ldp(ta, 42));
        float db = norm3(ldp(tb, lm) - ldp(tb, 42));
        o[91 + h] = (db - da) * 0.5f;
    }

    for (int h = 0; h < 2; ++h) {
        int base = h * 21;
        float ix = P(base + 8).x, mx = P(base + 12).x, rx = P(base + 16).x;
        o[93 + 2 * h + 0] = ix - mx;
        o[93 + 2 * h + 1] = mx - rx;
    }

    {
        V3 ldv = velW[0] * (1.0f / (norm3(velW[0]) + 1e-6f));
        V3 rdv = velW[1] * (1.0f / (norm3(velW[1]) + 1e-6f));
        o[97] = dot3(ldv, rdv);
    }

    o[98] = norm3(velW[0]);
    o[99] = norm3(velW[1]);
    o[100] = norm3(accAt(0, t));
    o[101] = norm3(accAt(21, t));

    {
        float hd = norm3(p0 - p21);
        o[102] = 1.0f / (1.0f + expf(-5.0f * (0.05f - hd)));
    }

    {
        V3 lsh = P(45), rsh = P(46);
        V3 shmid = (lsh + rsh) * 0.5f;
        float shw = dist3(lsh, rsh);
        float invw = 1.0f / (shw + 1e-6f);
        o[103] = (p0.y - shmid.y) * invw * bg;
        o[104] = (p0.x - shmid.x) * invw * bg;
        o[105] = dist3(p0, lsh) * bg;
        o[106] = dist3(p0, P(47)) * bg;
        o[107] = (p21.y - shmid.y) * invw * bg;
        o[108] = (p21.x - shmid.x) * invw * bg;
        o[109] = dist3(p21, rsh) * bg;
        o[110] = dist3(p21, P(48)) * bg;
        o[111] = shw * bg;
        V3 mouth = (P(49) + P(50)) * 0.5f;
        o[112] = dist3(p0, mouth) * bg;
        o[113] = dist3(p21, mouth) * bg;
    }
}

extern "C" void kernel_launch(void* const* d_in, const int* in_sizes, int n_in,
                              void* d_out, int out_size, void* d_ws, size_t ws_size,
                              hipStream_t stream) {
    const float* xyz   = (const float*)d_in[0];
    const float* fmask = (const float*)d_in[1];
    const float* bmask = (const float*)d_in[2];
    float* out = (float*)d_out;

    const int BT = in_sizes[1];   // B*T (face_mask element count)
    const int T  = 512;           // per reference setup_inputs

    if (T % TILE == 0 && BT % T == 0 && T >= 3 * TILE) {
        // 2048 one-wave blocks; LDS 19.2 KB -> 8 resident/CU (2 waves/SIMD)
        geo_fused<<<BT / TILE, TILE, 0, stream>>>(xyz, fmask, bmask, out, T);
    } else {
        const int threads = 256;
        geo_direct<<<(BT + threads - 1) / threads, threads, 0, stream>>>(
            xyz, fmask, bmask, out, BT, T);
    }
}

// Round 3
// 141.479 us; speedup vs baseline: 1.1509x; 1.0585x over previous
//
#include <hip/hip_runtime.h>
#include <math.h>

// ---------------------------------------------------------------------------
// GeoFeatureExtractor: B=256, T=512, N=51 landmarks x 3 (fp32), 114 features.
// Round 8: pair-lane tile. r7 post-mortem: phase-split staging refetched
// record-boundary lines (FETCH 51->90 MB) and exposed 2 DMA drains; the
// occupancy gain (9->15%) was eaten by +44 MB traffic.
// New structure: TILE=32 timesteps/block, 2 lanes per timestep (h=tid&1:
// even lane computes hand0-side features, odd lane hand1-side; the feature
// set is symmetric so both run the SAME instruction stream, only the h-offset
// in addresses differs -> zero divergence except 6 shared scalars).
//   - stage 32 FULL records (153 floats) = 19,584 B: global stride == LDS
//     stride -> pure LINEAR copy -> global_load_lds WIDTH 16: 20 DMA instrs
//     (vs 192), one drain point, every input byte read exactly once.
//   - + 144 B edge halo -> 19.7 KB LDS -> 8 blocks/CU resident.
//   - features held in named VGPRs (static indexing), then one LDS out-image
//     write phase (per-lane h-offset addresses) + r6 coalesced float4 burst.
// Kept: Hastings acos, __expf, v_rcp/v_sqrt, exact _cdiff boundary semantics.
// ---------------------------------------------------------------------------

#define NF   114
#define NC   153
#define TILE 32                  // timesteps per block (2 lanes each)
#define SFLOATS (TILE * NC)      // 4896 floats staged linearly (19,584 B)

#if defined(__has_builtin)
#if __has_builtin(__builtin_amdgcn_global_load_lds)
#define USE_DMA 1
#endif
#endif
#ifndef USE_DMA
#define USE_DMA 0
#endif

typedef const __attribute__((address_space(1))) void gas_t;
typedef __attribute__((address_space(3))) void las_t;

// width-16 DMA: per-lane global addr g; LDS dest = uniform base + lane*16
__device__ __forceinline__ void dma16(const float* g, float* lds) {
#if USE_DMA
    __builtin_amdgcn_global_load_lds((gas_t*)g, (las_t*)lds, 16, 0, 0);
#else
    *reinterpret_cast<float4*>(lds + (threadIdx.x & 63) * 4) =
        *reinterpret_cast<const float4*>(g);
#endif
}

struct V3 { float x, y, z; };

__device__ __forceinline__ V3 operator-(V3 a, V3 b) { return {a.x - b.x, a.y - b.y, a.z - b.z}; }
__device__ __forceinline__ V3 operator+(V3 a, V3 b) { return {a.x + b.x, a.y + b.y, a.z + b.z}; }
__device__ __forceinline__ V3 operator*(V3 a, float s) { return {a.x * s, a.y * s, a.z * s}; }
__device__ __forceinline__ float dot3(V3 a, V3 b) { return a.x * b.x + a.y * b.y + a.z * b.z; }
__device__ __forceinline__ V3 cross3(V3 a, V3 b) {
    return {a.y * b.z - a.z * b.y, a.z * b.x - a.x * b.z, a.x * b.y - a.y * b.x};
}

__device__ __forceinline__ float fsqrt(float x) { return __builtin_amdgcn_sqrtf(x); }
__device__ __forceinline__ float frcp(float x)  { return __builtin_amdgcn_rcpf(x); }

__device__ __forceinline__ float norm3(V3 a) { return fsqrt(dot3(a, a)); }
__device__ __forceinline__ float dist3(V3 a, V3 b) { V3 d = a - b; return fsqrt(dot3(d, d) + 1e-6f); }

// clip + Hastings acos approximation, |err| < 7e-5 rad
__device__ __forceinline__ float acosc(float c) {
    c = fminf(fmaxf(c, -1.0f + 1e-6f), 1.0f - 1e-6f);
    float ax = fabsf(c);
    float r = fsqrt(1.0f - ax) *
              (1.5707288f + ax * (-0.2121144f + ax * (0.0742610f - 0.0187293f * ax)));
    return c < 0.0f ? 3.14159265358979f - r : r;
}

// boundary-mapped central-diff endpoints (exact _cdiff semantics)
__device__ __forceinline__ void bmap(int tt, int T, int& ta, int& tb) {
    if (tt == 0)          { ta = 0;      tb = 2;     }
    else if (tt == T - 1) { ta = T - 3;  tb = T - 1; }
    else                  { ta = tt - 1; tb = tt + 1; }
}

__global__ __launch_bounds__(64, 2) void geo_fused(
    const float* __restrict__ xyz,
    const float* __restrict__ fmask,
    const float* __restrict__ bmask,
    float* __restrict__ out,
    int T)
{
    // S: [staging] 32 records x 153 floats, linear (== global layout)
    //    [epilogue overlay] out-image 32 rows x 114 floats (14,592 B < 19,584)
    __shared__ __align__(16) float S[SFLOATS];   // 19,584 B
    __shared__ float Hb[36];                     //    144 B: 4 edge recs x 9
                                                 // => 19,728 B -> 8 blocks/CU

    const int tid = threadIdx.x;                 // 0..63 (one wave)
    const int h   = tid & 1;                     // 0: hand0-side, 1: hand1-side
    const int r   = tid >> 1;                    // record 0..31
    const int tilesPerRow = T / TILE;
    const int b   = blockIdx.x / tilesPerRow;
    const int t0  = (blockIdx.x - b * tilesPerRow) * TILE;
    const int t   = t0 + r;
    const int bT0 = b * T;
    const int idx = bT0 + t;

    // gbase byte offset = 612*(bT0+t0); bT0+t0 is a multiple of 32 -> 16B aligned
    const float* gbase = xyz + (size_t)(bT0 + t0) * NC;

    // ===== staging: pure linear copy, width-16 DMA (20 instrs, 1 drain) ====
    #pragma unroll
    for (int i = 0; i < 19; ++i)                         // 19 x 1024 B
        dma16(gbase + i * 256 + tid * 4, S + i * 256);
    if (tid < 8)                                         // tail 128 B
        dma16(gbase + 19 * 256 + tid * 4, S + 19 * 256);

    // edge halo: 4 records (t0-2, t0-1, t0+TILE, t0+TILE+1) x 9 floats
    // layout per rec: {w0.xyz, w1.xyz, nose.xyz} at source offsets
    // (c/3)*63 + c%3 -> {0,1,2, 63,64,65, 126,127,128}
    if (tid < 36) {
        int e = tid / 9, c = tid - e * 9;
        int th = t0 + (e < 2 ? e - 2 : TILE - 2 + e);
        th = th < 0 ? 0 : (th > T - 1 ? T - 1 : th);
        int g3 = c / 3;
        int off = g3 * 63 + (c - g3 * 3);
        Hb[tid] = xyz[(size_t)(bT0 + th) * NC + off];
    }

    const float fg = fmask[idx];
    const float bg = bmask[idx];

    __syncthreads();   // drains DMA (vmcnt) + halo ds_writes; 1 wave -> cheap

    // ===== all compute -> named VGPRs ======================================
    const float* Rec = S + r * NC;           // this timestep's record
    const float* R   = Rec + h * 63;         // own hand base (0 or 63)

    auto PL = [&](int lm) -> V3 {
        int c = 3 * lm;
        return V3{R[c], R[c + 1], R[c + 2]};
    };

    // --- Block A: tips + curls + cross + d_ti (own hand) ---
    V3 t_tip = PL(4),  i_tip = PL(8),  m_tip = PL(12);
    V3 r_tip = PL(16), p_tip = PL(20);
    float a0 = dist3(t_tip, i_tip);
    float a1 = dist3(i_tip, m_tip);
    float a2 = dist3(m_tip, r_tip);
    float a3 = dist3(r_tip, p_tip);
    float a4 = dist3(t_tip, p_tip);
    V3 tm = PL(2),  tjj = PL(3);
    float a5 = dist3(tm, t_tip) * frcp(dist3(tm, tjj) + 1e-4f);
    V3 im = PL(5),  ijj = PL(6);
    float a6 = dist3(im, i_tip) * frcp(dist3(im, ijj) + 1e-4f);
    V3 mm = PL(9),  mjj = PL(10);
    float a7 = dist3(mm, m_tip) * frcp(dist3(mm, mjj) + 1e-4f);
    V3 rm = PL(13), rjj = PL(14);
    float a8 = dist3(rm, r_tip) * frcp(dist3(rm, rjj) + 1e-4f);
    V3 pm = PL(17), pjj = PL(18);
    float a9  = dist3(pm, p_tip) * frcp(dist3(pm, pjj) + 1e-4f);
    float a10 = i_tip.x - m_tip.x;
    float a11 = dist3(t_tip, im);
    // --- Block L: tip x-diffs (own hand) ---
    float l0 = a10;
    float l1 = m_tip.x - r_tip.x;

    // --- Block C: joint angles (own hand), static-indexed array ---
    constexpr int TRI[15][3] = {
        {0, 1, 2},   {1, 2, 3},   {2, 3, 4},
        {0, 5, 6},   {5, 6, 7},   {6, 7, 8},
        {0, 9, 10},  {9, 10, 11}, {10, 11, 12},
        {0, 13, 14}, {13, 14, 15},{14, 15, 16},
        {0, 17, 18}, {17, 18, 19},{18, 19, 20}};
    float cang[15];
    #pragma unroll
    for (int i = 0; i < 15; ++i) {
        V3 pjv = PL(TRI[i][1]);
        V3 v1 = PL(TRI[i][0]) - pjv;
        V3 v2 = PL(TRI[i][2]) - pjv;
        cang[i] = acosc(dot3(v1, v2) * frcp(norm3(v1) * norm3(v2) + 1e-6f));
    }

    // --- Blocks D/F: palm normal ; Block E: spread (own hand) ---
    V3 w = PL(0);                            // own wrist
    V3 nvec = cross3(PL(5) - w, PL(17) - w);
    nvec = nvec * frcp(norm3(nvec) + 1e-6f);
    V3 v5  = PL(5)  - w;
    V3 v9  = PL(9)  - w;
    V3 v13 = PL(13) - w;
    V3 v17 = PL(17) - w;
    float e0 = acosc(dot3(v5,  v9)  * frcp(norm3(v5)  * norm3(v9)  + 1e-6f));
    float e1 = acosc(dot3(v9,  v13) * frcp(norm3(v9)  * norm3(v13) + 1e-6f));
    float e2 = acosc(dot3(v13, v17) * frcp(norm3(v13) * norm3(v17) + 1e-6f));

    // --- temporal helpers: staging for rel in [0,32), Hb edges otherwise ---
    auto HP = [&](int cb, int th) -> V3 {    // cb in {0,3,6}: w0/w1/nose
        int rel = th - t0;
        const float* q;
        if (rel >= 0 && rel < TILE) q = S + rel * NC + cb * 21;
        else                        q = Hb + (rel < 0 ? rel + 2 : rel - (TILE - 2)) * 9 + cb;
        return V3{q[0], q[1], q[2]};
    };
    auto wvel = [&](int cb, int tt) -> V3 {
        int ta, tb; bmap(tt, T, ta, tb);
        return (HP(cb, tb) - HP(cb, ta)) * 0.5f;
    };
    auto wacc = [&](int cb, int tt) -> V3 {
        int ta, tb; bmap(tt, T, ta, tb);
        return (wvel(cb, tb) - wvel(cb, ta)) * 0.5f;
    };

    V3 velW0 = wvel(0, t), velW1 = wvel(3, t);
    V3 velOwn = {h ? velW1.x : velW0.x, h ? velW1.y : velW0.y, h ? velW1.z : velW0.z};

    // G: velocity direction (jnp.maximum eps), own hand
    float g_inv = frcp(fmaxf(norm3(velOwn), 1e-6f));
    float g0 = velOwn.x * g_inv, g1 = velOwn.y * g_inv, g2 = velOwn.z * g_inv;
    // H: velocity-turn angle (padded 0 at t = T-1), own hand
    float h_turn = 0.0f;
    if (t < T - 1) {
        V3 v1t = wvel(3 * h, t + 1);
        V3 aa = velOwn * frcp(norm3(velOwn) + 1e-6f);
        V3 cc = v1t * frcp(norm3(v1t) + 1e-6f);
        h_turn = acosc(dot3(aa, cc));
    }
    // K: d/dt of dist(wrist, nose), own hand (plain norm, no eps)
    float k_d;
    {
        int ta, tb; bmap(t, T, ta, tb);
        float da = norm3(HP(3 * h, ta) - HP(6, ta));
        float db = norm3(HP(3 * h, tb) - HP(6, tb));
        k_d = (db - da) * 0.5f;
    }
    // N: speed ; O: accel magnitude (own hand)
    float n_sp  = norm3(velOwn);
    float o_acc = norm3(wacc(3 * h, t));
    // shared scalars (both lanes compute; split on write)
    V3 p0h = HP(0, t), p21h = HP(3, t);
    float s88 = dist3(p0h, p21h);
    V3 relv = p21h - p0h;
    float rinv = frcp(norm3(relv) + 1e-6f);
    float s89 = relv.x * rinv, s90 = relv.y * rinv;
    V3 ldv = velW0 * frcp(norm3(velW0) + 1e-6f);
    V3 rdv = velW1 * frcp(norm3(velW1) + 1e-6f);
    float s97 = dot3(ldv, rdv);
    float hd = norm3(p0h - p21h);
    float s102 = frcp(1.0f + __expf(-5.0f * (0.05f - hd)));

    // --- face + body (own-wrist symmetric) ---
    auto FL = [&](int k) -> V3 {             // landmark 42+k
        const float* q = Rec + 126 + 3 * k;
        return V3{q[0], q[1], q[2]};
    };
    V3 nose = FL(0), chin = FL(1), fore = FL(2);
    float b0 = dist3(w, nose) * fg;
    float b1 = dist3(w, chin) * fg;
    float b2 = dist3(w, fore) * fg;
    float b3 = dist3(i_tip, nose) * fg;
    float b4 = dist3(i_tip, fore) * fg;
    V3 lsh = FL(3), rsh = FL(4);
    V3 shmid = (lsh + rsh) * 0.5f;
    float shw  = dist3(lsh, rsh);
    float invw = frcp(shw + 1e-6f);
    float q0 = (w.y - shmid.y) * invw * bg;
    float q1 = (w.x - shmid.x) * invw * bg;
    float q2 = dist3(w, FL(3 + h)) * bg;     // own shoulder
    float q3 = dist3(w, FL(5 + h)) * bg;     // own elbow
    float q111 = shw * bg;
    V3 mouth = (FL(7) + FL(8)) * 0.5f;
    float qm = dist3(w, mouth) * bg;

    // ===== out-image write (overlays staging; all S reads are done) ========
    __syncthreads();
    {
        float* W = S + r * NF;               // image row r; cols split by h
        W[12 * h + 0]  = a0;  W[12 * h + 1]  = a1;  W[12 * h + 2]  = a2;
        W[12 * h + 3]  = a3;  W[12 * h + 4]  = a4;  W[12 * h + 5]  = a5;
        W[12 * h + 6]  = a6;  W[12 * h + 7]  = a7;  W[12 * h + 8]  = a8;
        W[12 * h + 9]  = a9;  W[12 * h + 10] = a10; W[12 * h + 11] = a11;
        W[93 + 2 * h] = l0;  W[94 + 2 * h] = l1;
        #pragma unroll
        for (int i = 0; i < 15; ++i) W[34 + 15 * h + i] = cang[i];
        W[64 + 3 * h] = nvec.x; W[65 + 3 * h] = nvec.y; W[66 + 3 * h] = nvec.z;
        W[76 + 2 * h] = nvec.y; W[77 + 2 * h] = nvec.z;
        W[70 + 3 * h] = e0; W[71 + 3 * h] = e1; W[72 + 3 * h] = e2;
        W[80 + 3 * h] = g0; W[81 + 3 * h] = g1; W[82 + 3 * h] = g2;
        W[86 + h] = h_turn;
        W[91 + h] = k_d;
        W[98 + h] = n_sp;
        W[100 + h] = o_acc;
        W[24 + 3 * h] = b0; W[25 + 3 * h] = b1; W[26 + 3 * h] = b2;
        W[30 + 2 * h] = b3; W[31 + 2 * h] = b4;
        W[103 + 4 * h] = q0; W[104 + 4 * h] = q1;
        W[105 + 4 * h] = q2; W[106 + 4 * h] = q3;
        W[112 + h] = qm;
        if (h == 0) {
            W[88] = s88; W[89] = s89; W[90] = s90; W[102] = s102; W[111] = q111;
        } else {
            W[97] = s97;
        }
    }
    __syncthreads();

    // ===== coalesced burst store: 32 x 456 B = 912 float4 = 14*64 + 16 =====
    {
        float* dst = out + (size_t)(bT0 + t0) * NF;
        #pragma unroll
        for (int i = 0; i < 14; ++i) {
            const int o4 = (i * 64 + tid) * 4;
            float4 v = *reinterpret_cast<const float4*>(S + o4);
            *reinterpret_cast<float4*>(dst + o4) = v;
        }
        if (tid < 16) {
            const int o4 = (14 * 64 + tid) * 4;
            float4 v = *reinterpret_cast<const float4*>(S + o4);
            *reinterpret_cast<float4*>(dst + o4) = v;
        }
    }
}

// ---------------------------------------------------------------------------
// Fallback: direct kernel (correct for any shape)
// ---------------------------------------------------------------------------
__constant__ int c_TRI[15][3] = {
    {0, 1, 2},   {1, 2, 3},   {2, 3, 4},
    {0, 5, 6},   {5, 6, 7},   {6, 7, 8},
    {0, 9, 10},  {9, 10, 11}, {10, 11, 12},
    {0, 13, 14}, {13, 14, 15},{14, 15, 16},
    {0, 17, 18}, {17, 18, 19},{18, 19, 20}};

__global__ __launch_bounds__(256) void geo_direct(
    const float* __restrict__ xyz,
    const float* __restrict__ fmask,
    const float* __restrict__ bmask,
    float* __restrict__ out,
    int BT, int T)
{
    int idx = blockIdx.x * blockDim.x + threadIdx.x;
    if (idx >= BT) return;
    int b = idx / T;
    int t = idx - b * T;
    int bT0 = b * T;

    auto ldp = [&](int tt, int lm) -> V3 {
        const float* p = xyz + ((size_t)(bT0 + tt) * 51 + (size_t)lm) * 3;
        return V3{p[0], p[1], p[2]};
    };
    auto P = [&](int lm) -> V3 { return ldp(t, lm); };
    auto velAt = [&](int lm, int tt) -> V3 {
        int ta, tb; bmap(tt, T, ta, tb);
        return (ldp(tb, lm) - ldp(ta, lm)) * 0.5f;
    };
    auto accAt = [&](int lm, int tt) -> V3 {
        int ta, tb; bmap(tt, T, ta, tb);
        return (velAt(lm, tb) - velAt(lm, ta)) * 0.5f;
    };

    float fg = fmask[idx];
    float bg = bmask[idx];
    float* o = out + (size_t)idx * NF;

    for (int h = 0; h < 2; ++h) {
        int base = h * 21;
        V3 t_tip = P(base + 4),  i_tip = P(base + 8),  m_tip = P(base + 12);
        V3 r_tip = P(base + 16), p_tip = P(base + 20);
        float* oa = o + h * 12;
        oa[0] = dist3(t_tip, i_tip);
        oa[1] = dist3(i_tip, m_tip);
        oa[2] = dist3(m_tip, r_tip);
        oa[3] = dist3(r_tip, p_tip);
        oa[4] = dist3(t_tip, p_tip);
        V3 tm = P(base + 2),  tj = P(base + 3);
        oa[5] = dist3(tm, t_tip) / (dist3(tm, tj) + 1e-4f);
        V3 im = P(base + 5),  ij = P(base + 6);
        oa[6] = dist3(im, i_tip) / (dist3(im, ij) + 1e-4f);
        V3 mm = P(base + 9),  mj = P(base + 10);
        oa[7] = dist3(mm, m_tip) / (dist3(mm, mj) + 1e-4f);
        V3 rm = P(base + 13), rj = P(base + 14);
        oa[8] = dist3(rm, r_tip) / (dist3(rm, rj) + 1e-4f);
        V3 pm = P(base + 17), pj = P(base + 18);
        oa[9] = dist3(pm, p_tip) / (dist3(pm, pj) + 1e-4f);
        oa[10] = i_tip.x - m_tip.x;
        oa[11] = dist3(t_tip, im);
    }

    V3 p0 = P(0), p21 = P(21);
    V3 nose = P(42), chin = P(43), fore = P(44);
    V3 itip0 = P(8), itip1 = P(29);
    o[24] = dist3(p0, nose) * fg;
    o[25] = dist3(p0, chin) * fg;
    o[26] = dist3(p0, fore) * fg;
    o[27] = dist3(p21, nose) * fg;
    o[28] = dist3(p21, chin) * fg;
    o[29] = dist3(p21, fore) * fg;
    o[30] = dist3(itip0, nose) * fg;
    o[31] = dist3(itip0, fore) * fg;
    o[32] = dist3(itip1, nose) * fg;
    o[33] = dist3(itip1, fore) * fg;

    for (int h = 0; h < 2; ++h) {
        int base = h * 21;
        for (int i = 0; i < 15; ++i) {
            V3 pj = P(base + c_TRI[i][1]);
            V3 v1 = P(base + c_TRI[i][0]) - pj;
            V3 v2 = P(base + c_TRI[i][2]) - pj;
            o[34 + h * 15 + i] = acosc(dot3(v1, v2) / (norm3(v1) * norm3(v2) + 1e-6f));
        }
    }

    V3 nrm[2];
    for (int h = 0; h < 2; ++h) {
        int base = h * 21;
        V3 w = (h == 0) ? p0 : p21;
        V3 n = cross3(P(base + 5) - w, P(base + 17) - w);
        float inv = 1.0f / (norm3(n) + 1e-6f);
        n = n * inv;
        nrm[h] = n;
        o[64 + 3 * h + 0] = n.x;
        o[64 + 3 * h + 1] = n.y;
        o[64 + 3 * h + 2] = n.z;
    }

    for (int h = 0; h < 2; ++h) {
        int base = h * 21;
        V3 w = (h == 0) ? p0 : p21;
        V3 v5  = P(base + 5)  - w;
        V3 v9  = P(base + 9)  - w;
        V3 v13 = P(base + 13) - w;
        V3 v17 = P(base + 17) - w;
        o[70 + 3 * h + 0] = acosc(dot3(v5,  v9)  / (norm3(v5)  * norm3(v9)  + 1e-6f));
        o[70 + 3 * h + 1] = acosc(dot3(v9,  v13) / (norm3(v9)  * norm3(v13) + 1e-6f));
        o[70 + 3 * h + 2] = acosc(dot3(v13, v17) / (norm3(v13) * norm3(v17) + 1e-6f));
    }

    for (int h = 0; h < 2; ++h) {
        o[76 + 2 * h + 0] = nrm[h].y;
        o[76 + 2 * h + 1] = nrm[h].z;
    }

    V3 velW[2];
    for (int h = 0; h < 2; ++h) {
        V3 v = velAt(h * 21, t);
        velW[h] = v;
        float inv = 1.0f / fmaxf(norm3(v), 1e-6f);
        o[80 + 3 * h + 0] = v.x * inv;
        o[80 + 3 * h + 1] = v.y * inv;
        o[80 + 3 * h + 2] = v.z * inv;
    }

    for (int h = 0; h < 2; ++h) {
        float val = 0.0f;
        if (t < T - 1) {
            V3 v0 = velW[h];
            V3 v1 = velAt(h * 21, t + 1);
            V3 a = v0 * (1.0f / (norm3(v0) + 1e-6f));
            V3 c = v1 * (1.0f / (norm3(v1) + 1e-6f));
            val = acosc(dot3(a, c));
        }
        o[86 + h] = val;
    }

    o[88] = dist3(p0, p21);
    {
        V3 rel = p21 - p0;
        float inv = 1.0f / (norm3(rel) + 1e-6f);
        o[89] = rel.x * inv;
        o[90] = rel.y * inv;
    }

    for (int h = 0; h < 2; ++h) {
        int lm = h * 21;
        int ta, tb; bmap(t, T, ta, tb);
        float da = norm3(ldp(ta, lm) - ldp(ta, 42));
        float db = norm3(ldp(tb, lm) - ldp(tb, 42));
        o[91 + h] = (db - da) * 0.5f;
    }

    for (int h = 0; h < 2; ++h) {
        int base = h * 21;
        float ix = P(base + 8).x, mx = P(base + 12).x, rx = P(base + 16).x;
        o[93 + 2 * h + 0] = ix - mx;
        o[93 + 2 * h + 1] = mx - rx;
    }

    {
        V3 ldv = velW[0] * (1.0f / (norm3(velW[0]) + 1e-6f));
        V3 rdv = velW[1] * (1.0f / (norm3(velW[1]) + 1e-6f));
        o[97] = dot3(ldv, rdv);
    }

    o[98] = norm3(velW[0]);
    o[99] = norm3(velW[1]);
    o[100] = norm3(accAt(0, t));
    o[101] = norm3(accAt(21, t));

    {
        float hd = norm3(p0 - p21);
        o[102] = 1.0f / (1.0f + expf(-5.0f * (0.05f - hd)));
    }

    {
        V3 lsh = P(45), rsh = P(46);
        V3 shmid = (lsh + rsh) * 0.5f;
        float shw = dist3(lsh, rsh);
        float invw = 1.0f / (shw + 1e-6f);
        o[103] = (p0.y - shmid.y) * invw * bg;
        o[104] = (p0.x - shmid.x) * invw * bg;
        o[105] = dist3(p0, lsh) * bg;
        o[106] = dist3(p0, P(47)) * bg;
        o[107] = (p21.y - shmid.y) * invw * bg;
        o[108] = (p21.x - shmid.x) * invw * bg;
        o[109] = dist3(p21, rsh) * bg;
        o[110] = dist3(p21, P(48)) * bg;
        o[111] = shw * bg;
        V3 mouth = (P(49) + P(50)) * 0.5f;
        o[112] = dist3(p0, mouth) * bg;
        o[113] = dist3(p21, mouth) * bg;
    }
}

extern "C" void kernel_launch(void* const* d_in, const int* in_sizes, int n_in,
                              void* d_out, int out_size, void* d_ws, size_t ws_size,
                              hipStream_t stream) {
    const float* xyz   = (const float*)d_in[0];
    const float* fmask = (const float*)d_in[1];
    const float* bmask = (const float*)d_in[2];
    float* out = (float*)d_out;

    const int BT = in_sizes[1];   // B*T (face_mask element count)
    const int T  = 512;           // per reference setup_inputs

    if (T % TILE == 0 && BT % T == 0) {
        // 4096 one-wave blocks (2 lanes/timestep); 19.7 KB LDS -> 8 blocks/CU
        geo_fused<<<BT / TILE, TILE * 2, 0, stream>>>(xyz, fmask, bmask, out, T);
    } else {
        const int threads = 256;
        geo_direct<<<(BT + threads - 1) / threads, threads, 0, stream>>>(
            xyz, fmask, bmask, out, BT, T);
    }
}

// Round 6
// 140.027 us; speedup vs baseline: 1.1629x; 1.0104x over previous
//
#include <hip/hip_runtime.h>
#include <math.h>

// ---------------------------------------------------------------------------
// GeoFeatureExtractor: B=256, T=512, N=51 landmarks x 3 (fp32), 114 features.
// Round 11 == Round 10 resubmit (r10 bench died on container infra, no data).
// r10: r9 bugfix. r9's split DMA loop issued chunk j=19 as a FULL 1 KB DMA
// from wave1 (floats 4864..5119) overflowing S (4896 floats) into Hb ->
// corrupted halo -> temporal/angle features wrong (absmax 2.62 ~ pi).
// Fix: wave0 stages chunks {0,2,..,18}, wave1 {1,3,..,17} + 8-lane 128 B
// tail (floats 4864..4895) — exact r8 byte coverage, split across waves.
// Structure (from r9): 128-thread blocks = 2 waves sharing ONE 32-record
// staging buffer, wave-uniform role split (no intra-wave divergence):
//   wave0 GEOM  = A-block dists/curls, L, temporal, face+body, shared scalars
//   wave1 ANGLE = C-block 15 angles + E-spread 3 angles + palm normal (D/F)
// -> LDS/wave 9.8 KB -> 8 blocks x 2 waves = 16 waves/CU (2x TLP vs r8).
// Kept from r8: linear width-16 global_load_lds staging (single-touch reads),
// LDS out-image overlay + coalesced float4 burst store, Hastings acos,
// __expf, v_rcp/v_sqrt, exact _cdiff boundary semantics.
// ---------------------------------------------------------------------------

#define NF   114
#define NC   153
#define TILE 32                  // timesteps per block
#define SFLOATS (TILE * NC)      // 4896 floats staged linearly (19,584 B)

#if defined(__has_builtin)
#if __has_builtin(__builtin_amdgcn_global_load_lds)
#define USE_DMA 1
#endif
#endif
#ifndef USE_DMA
#define USE_DMA 0
#endif

typedef const __attribute__((address_space(1))) void gas_t;
typedef __attribute__((address_space(3))) void las_t;

// width-16 DMA: per-lane global addr g; LDS dest = wave-uniform base + lane*16
__device__ __forceinline__ void dma16(const float* g, float* lds) {
#if USE_DMA
    __builtin_amdgcn_global_load_lds((gas_t*)g, (las_t*)lds, 16, 0, 0);
#else
    *reinterpret_cast<float4*>(lds + (threadIdx.x & 63) * 4) =
        *reinterpret_cast<const float4*>(g);
#endif
}

struct V3 { float x, y, z; };

__device__ __forceinline__ V3 operator-(V3 a, V3 b) { return {a.x - b.x, a.y - b.y, a.z - b.z}; }
__device__ __forceinline__ V3 operator+(V3 a, V3 b) { return {a.x + b.x, a.y + b.y, a.z + b.z}; }
__device__ __forceinline__ V3 operator*(V3 a, float s) { return {a.x * s, a.y * s, a.z * s}; }
__device__ __forceinline__ float dot3(V3 a, V3 b) { return a.x * b.x + a.y * b.y + a.z * b.z; }
__device__ __forceinline__ V3 cross3(V3 a, V3 b) {
    return {a.y * b.z - a.z * b.y, a.z * b.x - a.x * b.z, a.x * b.y - a.y * b.x};
}

__device__ __forceinline__ float fsqrt(float x) { return __builtin_amdgcn_sqrtf(x); }
__device__ __forceinline__ float frcp(float x)  { return __builtin_amdgcn_rcpf(x); }

__device__ __forceinline__ float norm3(V3 a) { return fsqrt(dot3(a, a)); }
__device__ __forceinline__ float dist3(V3 a, V3 b) { V3 d = a - b; return fsqrt(dot3(d, d) + 1e-6f); }

// clip + Hastings acos approximation, |err| < 7e-5 rad
__device__ __forceinline__ float acosc(float c) {
    c = fminf(fmaxf(c, -1.0f + 1e-6f), 1.0f - 1e-6f);
    float ax = fabsf(c);
    float r = fsqrt(1.0f - ax) *
              (1.5707288f + ax * (-0.2121144f + ax * (0.0742610f - 0.0187293f * ax)));
    return c < 0.0f ? 3.14159265358979f - r : r;
}

// boundary-mapped central-diff endpoints (exact _cdiff semantics)
__device__ __forceinline__ void bmap(int tt, int T, int& ta, int& tb) {
    if (tt == 0)          { ta = 0;      tb = 2;     }
    else if (tt == T - 1) { ta = T - 3;  tb = T - 1; }
    else                  { ta = tt - 1; tb = tt + 1; }
}

__global__ __launch_bounds__(128, 4) void geo_fused(
    const float* __restrict__ xyz,
    const float* __restrict__ fmask,
    const float* __restrict__ bmask,
    float* __restrict__ out,
    int T)
{
    // S: [staging] 32 records x 153 floats, linear (== global layout)
    //    [epilogue overlay] out-image 32 rows x 114 floats (14,592 B < 19,584)
    __shared__ __align__(16) float S[SFLOATS];   // 19,584 B
    __shared__ float Hb[36];                     //    144 B -> 8 blocks/CU

    const int tid  = threadIdx.x;                // 0..127 (two waves)
    const int lane = tid & 63;
    const int wid  = tid >> 6;                   // 0: GEOM wave, 1: ANGLE wave
    const int h    = lane & 1;                   // hand side
    const int r    = lane >> 1;                  // record 0..31
    const int tilesPerRow = T / TILE;
    const int b    = blockIdx.x / tilesPerRow;
    const int t0   = (blockIdx.x - b * tilesPerRow) * TILE;
    const int t    = t0 + r;
    const int bT0  = b * T;
    const int idx  = bT0 + t;

    const float* gbase = xyz + (size_t)(bT0 + t0) * NC;

    // ===== staging: 19 full 1KB chunks + 128B tail, split across waves =====
    // wave0: chunks 0,2,..,18 (10); wave1: chunks 1,3,..,17 (9) + tail.
    // BUGFIX vs r9: chunk j=19 must NOT be a full 1KB DMA (would overflow S
    // into Hb and read past xyz on the last block).
    #pragma unroll
    for (int i = 0; i < 10; ++i) {
        const int j = 2 * i + wid;
        if (j < 19)
            dma16(gbase + j * 256 + lane * 4, S + j * 256);
    }
    if (wid == 1 && lane < 8)                    // tail: floats 4864..4895
        dma16(gbase + 19 * 256 + lane * 4, S + 19 * 256);

    // edge halo: 4 records (t0-2, t0-1, t0+TILE, t0+TILE+1) x 9 floats
    // per rec: {w0.xyz, w1.xyz, nose.xyz} at source offsets {0..2,63..65,126..128}
    if (tid < 36) {
        int e = tid / 9, c = tid - e * 9;
        int th = t0 + (e < 2 ? e - 2 : TILE - 2 + e);
        th = th < 0 ? 0 : (th > T - 1 ? T - 1 : th);
        int g3 = c / 3;
        Hb[tid] = xyz[(size_t)(bT0 + th) * NC + g3 * 63 + (c - g3 * 3)];
    }

    float fg = 0.0f, bg = 0.0f;
    if (wid == 0) { fg = fmask[idx]; bg = bmask[idx]; }

    __syncthreads();   // both waves' DMAs + halo visible

    // ===== compute (wave-uniform role split) ==============================
    const float* Rec = S + r * NC;               // this timestep's record
    const float* R   = Rec + h * 63;             // own hand base (0 or 63)
    auto PL = [&](int lm) -> V3 {
        int c = 3 * lm;
        return V3{R[c], R[c + 1], R[c + 2]};
    };

    // wave1 (ANGLE) outputs
    float cang[15];
    V3 nvec;
    float e0, e1, e2;
    // wave0 (GEOM) outputs
    float a0, a1, a2, a3, a4, a5, a6, a7, a8, a9, a10, a11, l1;
    float g0, g1, g2, h_turn, k_d, n_sp, o_acc;
    float b0, b1, b2, b3, b4;
    float q0, q1, q2, q3, q111, qm;
    float s88, s89, s90, s97, s102;

    if (wid == 1) {
        // --- Block C: joint angles (own hand) ---
        constexpr int TRI[15][3] = {
            {0, 1, 2},   {1, 2, 3},   {2, 3, 4},
            {0, 5, 6},   {5, 6, 7},   {6, 7, 8},
            {0, 9, 10},  {9, 10, 11}, {10, 11, 12},
            {0, 13, 14}, {13, 14, 15},{14, 15, 16},
            {0, 17, 18}, {17, 18, 19},{18, 19, 20}};
        #pragma unroll
        for (int i = 0; i < 15; ++i) {
            V3 pjv = PL(TRI[i][1]);
            V3 v1 = PL(TRI[i][0]) - pjv;
            V3 v2 = PL(TRI[i][2]) - pjv;
            cang[i] = acosc(dot3(v1, v2) * frcp(norm3(v1) * norm3(v2) + 1e-6f));
        }
        // --- Blocks D/F: palm normal ; Block E: spread (own hand) ---
        V3 w = PL(0);
        nvec = cross3(PL(5) - w, PL(17) - w);
        nvec = nvec * frcp(norm3(nvec) + 1e-6f);
        V3 v5  = PL(5)  - w;
        V3 v9  = PL(9)  - w;
        V3 v13 = PL(13) - w;
        V3 v17 = PL(17) - w;
        e0 = acosc(dot3(v5,  v9)  * frcp(norm3(v5)  * norm3(v9)  + 1e-6f));
        e1 = acosc(dot3(v9,  v13) * frcp(norm3(v9)  * norm3(v13) + 1e-6f));
        e2 = acosc(dot3(v13, v17) * frcp(norm3(v13) * norm3(v17) + 1e-6f));
    } else {
        // --- Block A: tips + curls + cross + d_ti (own hand) ---
        V3 t_tip = PL(4),  i_tip = PL(8),  m_tip = PL(12);
        V3 r_tip = PL(16), p_tip = PL(20);
        a0 = dist3(t_tip, i_tip);
        a1 = dist3(i_tip, m_tip);
        a2 = dist3(m_tip, r_tip);
        a3 = dist3(r_tip, p_tip);
        a4 = dist3(t_tip, p_tip);
        V3 tm = PL(2),  tjj = PL(3);
        a5 = dist3(tm, t_tip) * frcp(dist3(tm, tjj) + 1e-4f);
        V3 im = PL(5),  ijj = PL(6);
        a6 = dist3(im, i_tip) * frcp(dist3(im, ijj) + 1e-4f);
        V3 mm = PL(9),  mjj = PL(10);
        a7 = dist3(mm, m_tip) * frcp(dist3(mm, mjj) + 1e-4f);
        V3 rm = PL(13), rjj = PL(14);
        a8 = dist3(rm, r_tip) * frcp(dist3(rm, rjj) + 1e-4f);
        V3 pm = PL(17), pjj = PL(18);
        a9  = dist3(pm, p_tip) * frcp(dist3(pm, pjj) + 1e-4f);
        a10 = i_tip.x - m_tip.x;
        a11 = dist3(t_tip, im);
        l1  = m_tip.x - r_tip.x;

        // --- temporal: staging for rel in [0,32), Hb edges otherwise ---
        auto HP = [&](int cb, int th) -> V3 {    // cb in {0,3,6}: w0/w1/nose
            int rel = th - t0;
            const float* q;
            if (rel >= 0 && rel < TILE) q = S + rel * NC + cb * 21;
            else q = Hb + (rel < 0 ? rel + 2 : rel - (TILE - 2)) * 9 + cb;
            return V3{q[0], q[1], q[2]};
        };
        auto wvel = [&](int cb, int tt) -> V3 {
            int ta, tb; bmap(tt, T, ta, tb);
            return (HP(cb, tb) - HP(cb, ta)) * 0.5f;
        };
        auto wacc = [&](int cb, int tt) -> V3 {
            int ta, tb; bmap(tt, T, ta, tb);
            return (wvel(cb, tb) - wvel(cb, ta)) * 0.5f;
        };

        V3 velW0 = wvel(0, t), velW1 = wvel(3, t);
        V3 velOwn = {h ? velW1.x : velW0.x, h ? velW1.y : velW0.y,
                     h ? velW1.z : velW0.z};

        // G: velocity direction (jnp.maximum eps), own hand
        float g_inv = frcp(fmaxf(norm3(velOwn), 1e-6f));
        g0 = velOwn.x * g_inv; g1 = velOwn.y * g_inv; g2 = velOwn.z * g_inv;
        // H: velocity-turn angle (padded 0 at t = T-1), own hand
        h_turn = 0.0f;
        if (t < T - 1) {
            V3 v1t = wvel(3 * h, t + 1);
            V3 aa = velOwn * frcp(norm3(velOwn) + 1e-6f);
            V3 cc = v1t * frcp(norm3(v1t) + 1e-6f);
            h_turn = acosc(dot3(aa, cc));
        }
        // K: d/dt of dist(wrist, nose), own hand (plain norm, no eps)
        {
            int ta, tb; bmap(t, T, ta, tb);
            float da = norm3(HP(3 * h, ta) - HP(6, ta));
            float db = norm3(HP(3 * h, tb) - HP(6, tb));
            k_d = (db - da) * 0.5f;
        }
        // N: speed ; O: accel magnitude (own hand)
        n_sp  = norm3(velOwn);
        o_acc = norm3(wacc(3 * h, t));
        // shared scalars (both lanes compute; split on write)
        V3 p0h = HP(0, t), p21h = HP(3, t);
        s88 = dist3(p0h, p21h);
        V3 relv = p21h - p0h;
        float rinv = frcp(norm3(relv) + 1e-6f);
        s89 = relv.x * rinv; s90 = relv.y * rinv;
        V3 ldv = velW0 * frcp(norm3(velW0) + 1e-6f);
        V3 rdv = velW1 * frcp(norm3(velW1) + 1e-6f);
        s97 = dot3(ldv, rdv);
        float hd = norm3(p0h - p21h);
        s102 = frcp(1.0f + __expf(-5.0f * (0.05f - hd)));

        // --- face + body (own-wrist symmetric) ---
        V3 w = PL(0);
        auto FL = [&](int k) -> V3 {             // landmark 42+k
            const float* q = Rec + 126 + 3 * k;
            return V3{q[0], q[1], q[2]};
        };
        V3 nose = FL(0), chin = FL(1), fore = FL(2);
        b0 = dist3(w, nose) * fg;
        b1 = dist3(w, chin) * fg;
        b2 = dist3(w, fore) * fg;
        b3 = dist3(i_tip, nose) * fg;
        b4 = dist3(i_tip, fore) * fg;
        V3 lsh = FL(3), rsh = FL(4);
        V3 shmid = (lsh + rsh) * 0.5f;
        float shw  = dist3(lsh, rsh);
        float invw = frcp(shw + 1e-6f);
        q0 = (w.y - shmid.y) * invw * bg;
        q1 = (w.x - shmid.x) * invw * bg;
        q2 = dist3(w, FL(3 + h)) * bg;           // own shoulder
        q3 = dist3(w, FL(5 + h)) * bg;           // own elbow
        q111 = shw * bg;
        V3 mouth = (FL(7) + FL(8)) * 0.5f;
        qm = dist3(w, mouth) * bg;
    }

    // ===== out-image write (overlays staging; all S reads are done) ========
    __syncthreads();
    {
        float* W = S + r * NF;                   // image row r; cols by h/role
        if (wid == 1) {
            #pragma unroll
            for (int i = 0; i < 15; ++i) W[34 + 15 * h + i] = cang[i];
            W[64 + 3 * h] = nvec.x; W[65 + 3 * h] = nvec.y; W[66 + 3 * h] = nvec.z;
            W[76 + 2 * h] = nvec.y; W[77 + 2 * h] = nvec.z;
            W[70 + 3 * h] = e0; W[71 + 3 * h] = e1; W[72 + 3 * h] = e2;
        } else {
            W[12 * h + 0]  = a0;  W[12 * h + 1]  = a1;  W[12 * h + 2]  = a2;
            W[12 * h + 3]  = a3;  W[12 * h + 4]  = a4;  W[12 * h + 5]  = a5;
            W[12 * h + 6]  = a6;  W[12 * h + 7]  = a7;  W[12 * h + 8]  = a8;
            W[12 * h + 9]  = a9;  W[12 * h + 10] = a10; W[12 * h + 11] = a11;
            W[93 + 2 * h] = a10; W[94 + 2 * h] = l1;
            W[80 + 3 * h] = g0; W[81 + 3 * h] = g1; W[82 + 3 * h] = g2;
            W[86 + h]  = h_turn;
            W[91 + h]  = k_d;
            W[98 + h]  = n_sp;
            W[100 + h] = o_acc;
            W[24 + 3 * h] = b0; W[25 + 3 * h] = b1; W[26 + 3 * h] = b2;
            W[30 + 2 * h] = b3; W[31 + 2 * h] = b4;
            W[103 + 4 * h] = q0; W[104 + 4 * h] = q1;
            W[105 + 4 * h] = q2; W[106 + 4 * h] = q3;
            W[112 + h] = qm;
            if (h == 0) {
                W[88] = s88; W[89] = s89; W[90] = s90;
                W[102] = s102; W[111] = q111;
            } else {
                W[97] = s97;
            }
        }
    }
    __syncthreads();

    // ===== coalesced burst store: 32 x 456 B = 912 float4 = 7*128 + 16 =====
    {
        float* dst = out + (size_t)(bT0 + t0) * NF;
        #pragma unroll
        for (int i = 0; i < 7; ++i) {
            const int o4 = (i * 128 + tid) * 4;
            float4 v = *reinterpret_cast<const float4*>(S + o4);
            *reinterpret_cast<float4*>(dst + o4) = v;
        }
        if (tid < 16) {
            const int o4 = (7 * 128 + tid) * 4;
            float4 v = *reinterpret_cast<const float4*>(S + o4);
            *reinterpret_cast<float4*>(dst + o4) = v;
        }
    }
}

// ---------------------------------------------------------------------------
// Fallback: direct kernel (correct for any shape)
// ---------------------------------------------------------------------------
__constant__ int c_TRI[15][3] = {
    {0, 1, 2},   {1, 2, 3},   {2, 3, 4},
    {0, 5, 6},   {5, 6, 7},   {6, 7, 8},
    {0, 9, 10},  {9, 10, 11}, {10, 11, 12},
    {0, 13, 14}, {13, 14, 15},{14, 15, 16},
    {0, 17, 18}, {17, 18, 19},{18, 19, 20}};

__global__ __launch_bounds__(256) void geo_direct(
    const float* __restrict__ xyz,
    const float* __restrict__ fmask,
    const float* __restrict__ bmask,
    float* __restrict__ out,
    int BT, int T)
{
    int idx = blockIdx.x * blockDim.x + threadIdx.x;
    if (idx >= BT) return;
    int b = idx / T;
    int t = idx - b * T;
    int bT0 = b * T;

    auto ldp = [&](int tt, int lm) -> V3 {
        const float* p = xyz + ((size_t)(bT0 + tt) * 51 + (size_t)lm) * 3;
        return V3{p[0], p[1], p[2]};
    };
    auto P = [&](int lm) -> V3 { return ldp(t, lm); };
    auto velAt = [&](int lm, int tt) -> V3 {
        int ta, tb; bmap(tt, T, ta, tb);
        return (ldp(tb, lm) - ldp(ta, lm)) * 0.5f;
    };
    auto accAt = [&](int lm, int tt) -> V3 {
        int ta, tb; bmap(tt, T, ta, tb);
        return (velAt(lm, tb) - velAt(lm, ta)) * 0.5f;
    };

    float fg = fmask[idx];
    float bg = bmask[idx];
    float* o = out + (size_t)idx * NF;

    for (int h = 0; h < 2; ++h) {
        int base = h * 21;
        V3 t_tip = P(base + 4),  i_tip = P(base + 8),  m_tip = P(base + 12);
        V3 r_tip = P(base + 16), p_tip = P(base + 20);
        float* oa = o + h * 12;
        oa[0] = dist3(t_tip, i_tip);
        oa[1] = dist3(i_tip, m_tip);
        oa[2] = dist3(m_tip, r_tip);
        oa[3] = dist3(r_tip, p_tip);
        oa[4] = dist3(t_tip, p_tip);
        V3 tm = P(base + 2),  tj = P(base + 3);
        oa[5] = dist3(tm, t_tip) / (dist3(tm, tj) + 1e-4f);
        V3 im = P(base + 5),  ij = P(base + 6);
        oa[6] = dist3(im, i_tip) / (dist3(im, ij) + 1e-4f);
        V3 mm = P(base + 9),  mj = P(base + 10);
        oa[7] = dist3(mm, m_tip) / (dist3(mm, mj) + 1e-4f);
        V3 rm = P(base + 13), rj = P(base + 14);
        oa[8] = dist3(rm, r_tip) / (dist3(rm, rj) + 1e-4f);
        V3 pm = P(base + 17), pj = P(base + 18);
        oa[9] = dist3(pm, p_tip) / (dist3(pm, pj) + 1e-4f);
        oa[10] = i_tip.x - m_tip.x;
        oa[11] = dist3(t_tip, im);
    }

    V3 p0 = P(0), p21 = P(21);
    V3 nose = P(42), chin = P(43), fore = P(44);
    V3 itip0 = P(8), itip1 = P(29);
    o[24] = dist3(p0, nose) * fg;
    o[25] = dist3(p0, chin) * fg;
    o[26] = dist3(p0, fore) * fg;
    o[27] = dist3(p21, nose) * fg;
    o[28] = dist3(p21, chin) * fg;
    o[29] = dist3(p21, fore) * fg;
    o[30] = dist3(itip0, nose) * fg;
    o[31] = dist3(itip0, fore) * fg;
    o[32] = dist3(itip1, nose) * fg;
    o[33] = dist3(itip1, fore) * fg;

    for (int h = 0; h < 2; ++h) {
        int base = h * 21;
        for (int i = 0; i < 15; ++i) {
            V3 pj = P(base + c_TRI[i][1]);
            V3 v1 = P(base + c_TRI[i][0]) - pj;
            V3 v2 = P(base + c_TRI[i][2]) - pj;
            o[34 + h * 15 + i] = acosc(dot3(v1, v2) / (norm3(v1) * norm3(v2) + 1e-6f));
        }
    }

    V3 nrm[2];
    for (int h = 0; h < 2; ++h) {
        int base = h * 21;
        V3 w = (h == 0) ? p0 : p21;
        V3 n = cross3(P(base + 5) - w, P(base + 17) - w);
        float inv = 1.0f / (norm3(n) + 1e-6f);
        n = n * inv;
        nrm[h] = n;
        o[64 + 3 * h + 0] = n.x;
        o[64 + 3 * h + 1] = n.y;
        o[64 + 3 * h + 2] = n.z;
    }

    for (int h = 0; h < 2; ++h) {
        int base = h * 21;
        V3 w = (h == 0) ? p0 : p21;
        V3 v5  = P(base + 5)  - w;
        V3 v9  = P(base + 9)  - w;
        V3 v13 = P(base + 13) - w;
        V3 v17 = P(base + 17) - w;
        o[70 + 3 * h + 0] = acosc(dot3(v5,  v9)  / (norm3(v5)  * norm3(v9)  + 1e-6f));
        o[70 + 3 * h + 1] = acosc(dot3(v9,  v13) / (norm3(v9)  * norm3(v13) + 1e-6f));
        o[70 + 3 * h + 2] = acosc(dot3(v13, v17) / (norm3(v13) * norm3(v17) + 1e-6f));
    }

    for (int h = 0; h < 2; ++h) {
        o[76 + 2 * h + 0] = nrm[h].y;
        o[76 + 2 * h + 1] = nrm[h].z;
    }

    V3 velW[2];
    for (int h = 0; h < 2; ++h) {
        V3 v = velAt(h * 21, t);
        velW[h] = v;
        float inv = 1.0f / fmaxf(norm3(v), 1e-6f);
        o[80 + 3 * h + 0] = v.x * inv;
        o[80 + 3 * h + 1] = v.y * inv;
        o[80 + 3 * h + 2] = v.z * inv;
    }

    for (int h = 0; h < 2; ++h) {
        float val = 0.0f;
        if (t < T - 1) {
            V3 v0 = velW[h];
            V3 v1 = velAt(h * 21, t + 1);
            V3 a = v0 * (1.0f / (norm3(v0) + 1e-6f));
            V3 c = v1 * (1.0f / (norm3(v1) + 1e-6f));
            val = acosc(dot3(a, c));
        }
        o[86 + h] = val;
    }

    o[88] = dist3(p0, p21);
    {
        V3 rel = p21 - p0;
        float inv = 1.0f / (norm3(rel) + 1e-6f);
        o[89] = rel.x * inv;
        o[90] = rel.y * inv;
    }

    for (int h = 0; h < 2; ++h) {
        int lm = h * 21;
        int ta, tb; bmap(t, T, ta, tb);
        float da = norm3(ldp(ta, lm) - ldp(ta, 42));
        float db = norm3(ldp(tb, lm) - ldp(tb, 42));
        o[91 + h] = (db - da) * 0.5f;
    }

    for (int h = 0; h < 2; ++h) {
        int base = h * 21;
        float ix = P(base + 8).x, mx = P(base + 12).x, rx = P(base + 16).x;
        o[93 + 2 * h + 0] = ix - mx;
        o[93 + 2 * h + 1] = mx - rx;
    }

    {
        V3 ldv = velW[0] * (1.0f / (norm3(velW[0]) + 1e-6f));
        V3 rdv = velW[1] * (1.0f / (norm3(velW[1]) + 1e-6f));
        o[97] = dot3(ldv, rdv);
    }

    o[98] = norm3(velW[0]);
    o[99] = norm3(velW[1]);
    o[100] = norm3(accAt(0, t));
    o[101] = norm3(accAt(21, t));

    {
        float hd = norm3(p0 - p21);
        o[102] = 1.0f / (1.0f + expf(-5.0f * (0.05f - hd)));
    }

    {
        V3 lsh = P(45), rsh = P(46);
        V3 shmid = (lsh + rsh) * 0.5f;
        float shw = dist3(lsh, rsh);
        float invw = 1.0f / (shw + 1e-6f);
        o[103] = (p0.y - shmid.y) * invw * bg;
        o[104] = (p0.x - shmid.x) * invw * bg;
        o[105] = dist3(p0, lsh) * bg;
        o[106] = dist3(p0, P(47)) * bg;
        o[107] = (p21.y - shmid.y) * invw * bg;
        o[108] = (p21.x - shmid.x) * invw * bg;
        o[109] = dist3(p21, rsh) * bg;
        o[110] = dist3(p21, P(48)) * bg;
        o[111] = shw * bg;
        V3 mouth = (P(49) + P(50)) * 0.5f;
        o[112] = dist3(p0, mouth) * bg;
        o[113] = dist3(p21, mouth) * bg;
    }
}

extern "C" void kernel_launch(void* const* d_in, const int* in_sizes, int n_in,
                              void* d_out, int out_size, void* d_ws, size_t ws_size,
                              hipStream_t stream) {
    const float* xyz   = (const float*)d_in[0];
    const float* fmask = (const float*)d_in[1];
    const float* bmask = (const float*)d_in[2];
    float* out = (float*)d_out;

    const int BT = in_sizes[1];   // B*T (face_mask element count)
    const int T  = 512;           // per reference setup_inputs

    if (T % TILE == 0 && BT % T == 0) {
        // 4096 blocks x 2 waves (role-split); 19.7 KB LDS -> 8 blocks/CU
        // = 16 waves/CU
        geo_fused<<<BT / TILE, 128, 0, stream>>>(xyz, fmask, bmask, out, T);
    } else {
        const int threads = 256;
        geo_direct<<<(BT + threads - 1) / threads, threads, 0, stream>>>(
            xyz, fmask, bmask, out, BT, T);
    }
}